// Round 3
// baseline (264.801 us; speedup 1.0000x reference)
//
#include <hip/hip_runtime.h>
#include <stdint.h>

typedef __attribute__((ext_vector_type(8))) short bf16x8;
typedef __attribute__((ext_vector_type(4))) float f32x4;
typedef __attribute__((ext_vector_type(4))) unsigned int u32x4;

#define NB 2
#define NL 2048
#define ND 768
#define NH 12
#define NDK 64
#define NM 4096   // NB*NL

__device__ __forceinline__ unsigned short f2bf(float f) {
  unsigned u = __builtin_bit_cast(unsigned, f);
  u += 0x7FFFu + ((u >> 16) & 1u);          // RNE
  return (unsigned short)(u >> 16);
}

__device__ __forceinline__ void gl_lds16(const unsigned short* g, unsigned short* l) {
  __builtin_amdgcn_global_load_lds((const __attribute__((address_space(1))) void*)g,
                                   (__attribute__((address_space(3))) void*)l, 16, 0, 0);
}

// ---- T5 relative-position bias table: bias_tab[h][d+2047], d = k - q ----
__global__ void k_bias(const float* __restrict__ rel_emb, float* __restrict__ bias_tab) {
  int idx = blockIdx.x * 256 + threadIdx.x;
  if (idx >= 4095 * NH) return;
  int h = idx % NH;
  int di = idx / NH;
  int rel = di - 2047;          // rel = k - q
  int n = -rel;
  int ret = 0;
  if (n < 0) { ret = 16; n = -n; }
  int b;
  if (n < 8) {
    b = ret + n;
  } else {
    int v = (n >= 91) ? 7 : (n >= 64) ? 6 : (n >= 46) ? 5 : (n >= 32) ? 4
          : (n >= 23) ? 3 : (n >= 16) ? 2 : (n >= 12) ? 1 : 0;
    b = ret + 8 + v;
  }
  bias_tab[h * 4095 + di] = rel_emb[b * NH + h];
}

// ---- fp32 -> bf16 (vectorized), optional scale ----
__global__ void k_conv(const float* __restrict__ src, unsigned short* __restrict__ dst,
                       int n4, float scale) {
  int i = blockIdx.x * 256 + threadIdx.x;
  if (i >= n4) return;
  float4 v = ((const float4*)src)[i];
  ushort4 o;
  o.x = f2bf(v.x * scale);
  o.y = f2bf(v.y * scale);
  o.z = f2bf(v.z * scale);
  o.w = f2bf(v.w * scale);
  ((ushort4*)dst)[i] = o;
}

// ---- W [K][N] fp32 -> Wt [N][K] bf16 (768x768), 4 matrices selected by z ----
__global__ void k_wt(const float* __restrict__ w0, const float* __restrict__ w1,
                     const float* __restrict__ w2, const float* __restrict__ w3,
                     unsigned short* __restrict__ o0, unsigned short* __restrict__ o1,
                     unsigned short* __restrict__ o2, unsigned short* __restrict__ o3) {
  const float* w = (blockIdx.z == 0) ? w0 : (blockIdx.z == 1) ? w1 : (blockIdx.z == 2) ? w2 : w3;
  unsigned short* o = (blockIdx.z == 0) ? o0 : (blockIdx.z == 1) ? o1 : (blockIdx.z == 2) ? o2 : o3;
  __shared__ float t[32][33];
  int bx = blockIdx.x * 32, by = blockIdx.y * 32;
  int tx = threadIdx.x, ty = threadIdx.y;
  for (int r = 0; r < 32; r += 8)
    t[ty + r][tx] = w[(by + ty + r) * ND + bx + tx];
  __syncthreads();
  for (int r = 0; r < 32; r += 8)
    o[(bx + ty + r) * ND + by + tx] = f2bf(t[tx][ty + r]);
}

// ---- bf16 MFMA GEMM: C[M,N] = A[M,K]*Bt[N,K]^T. 64x64 tile, BK=64, dbuf LDS,
// global_load_lds w16, XOR-swizzled (col16 ^= row&7, inverse-swz global source).
// mode 0: bf16 row-major out; 1: fp32 row-major out; 2: bf16 Vt out [B][768][L]
__global__ __launch_bounds__(256) void k_gemm(const unsigned short* __restrict__ A,
                                              const unsigned short* __restrict__ Bt,
                                              void* __restrict__ Cout,
                                              int Msz, int Nsz, int Ksz, int mode) {
  __shared__ unsigned short As[2][4096];   // [64 rows][64 k] linear, 8 KB each
  __shared__ unsigned short Bs[2][4096];
  int tid = threadIdx.x;
  int wave = tid >> 6, lane = tid & 63;
  int lr = lane & 15, lg = lane >> 4;
  int m0 = blockIdx.x * 64, n0 = blockIdx.y * 64;
  int wm = (wave >> 1) * 32, wn = (wave & 1) * 32;
  // staging map: thread covers LDS bytes tid*16 (+4096B for chunk1), row=tid>>3 (+32)
  int srow = tid >> 3, spc = tid & 7;
  int sg = spc ^ (srow & 7);                       // inverse swizzle on global source
  const unsigned short* Ag0 = A  + (size_t)(m0 + srow) * Ksz + sg * 8;
  const unsigned short* Ag1 = A  + (size_t)(m0 + 32 + srow) * Ksz + sg * 8;
  const unsigned short* Bg0 = Bt + (size_t)(n0 + srow) * Ksz + sg * 8;
  const unsigned short* Bg1 = Bt + (size_t)(n0 + 32 + srow) * Ksz + sg * 8;
  f32x4 acc[2][2] = {};
  const int KT = Ksz >> 6;
  // prologue: stage tile 0 into buf 0
  gl_lds16(Ag0, &As[0][tid * 8]);
  gl_lds16(Ag1, &As[0][2048 + tid * 8]);
  gl_lds16(Bg0, &Bs[0][tid * 8]);
  gl_lds16(Bg1, &Bs[0][2048 + tid * 8]);
  __syncthreads();
  int cur = 0;
  for (int t = 0; t < KT; ++t) {
    if (t + 1 < KT) {
      int k0 = (t + 1) << 6;
      gl_lds16(Ag0 + k0, &As[cur ^ 1][tid * 8]);
      gl_lds16(Ag1 + k0, &As[cur ^ 1][2048 + tid * 8]);
      gl_lds16(Bg0 + k0, &Bs[cur ^ 1][tid * 8]);
      gl_lds16(Bg1 + k0, &Bs[cur ^ 1][2048 + tid * 8]);
    }
#pragma unroll
    for (int ks = 0; ks < 2; ++ks) {
      bf16x8 af[2], bfr[2];
#pragma unroll
      for (int i = 0; i < 2; ++i) {
        int ar = wm + i * 16 + lr;
        af[i] = *(const bf16x8*)&As[cur][ar * 64 + (((ks * 4 + lg) ^ (ar & 7)) * 8)];
        int br = wn + i * 16 + lr;
        bfr[i] = *(const bf16x8*)&Bs[cur][br * 64 + (((ks * 4 + lg) ^ (br & 7)) * 8)];
      }
#pragma unroll
      for (int mi = 0; mi < 2; ++mi)
#pragma unroll
        for (int ni = 0; ni < 2; ++ni)
          acc[mi][ni] = __builtin_amdgcn_mfma_f32_16x16x32_bf16(af[mi], bfr[ni], acc[mi][ni], 0, 0, 0);
    }
    __syncthreads();   // drains vmcnt (prefetch done) + protects buffer swap
    cur ^= 1;
  }
#pragma unroll
  for (int mi = 0; mi < 2; ++mi)
#pragma unroll
    for (int ni = 0; ni < 2; ++ni)
#pragma unroll
      for (int r = 0; r < 4; ++r) {
        int row = m0 + wm + mi * 16 + lg * 4 + r;   // C/D: col=lane&15, row=(lane>>4)*4+reg
        int col = n0 + wn + ni * 16 + lr;
        float v = acc[mi][ni][r];
        if (mode == 0) {
          ((unsigned short*)Cout)[(size_t)row * Nsz + col] = f2bf(v);
        } else if (mode == 1) {
          ((float*)Cout)[(size_t)row * Nsz + col] = v;
        } else {
          int bb = row >> 11, l = row & 2047;       // Vt[(b*768+col)][l]
          ((unsigned short*)Cout)[(((size_t)bb * ND + col) << 11) + l] = f2bf(v);
        }
      }
}

// ---- fused flash attention: one (b,h,64-row q-tile) per block, 4 waves x 16 rows.
// K/V fragments read DIRECTLY from global (L2-resident), prefetched one step ahead.
// LDS only for P transpose + bias window. 2 barriers/iter.
__global__ __launch_bounds__(256) void k_attn(const unsigned short* __restrict__ Qb,
                                              const unsigned short* __restrict__ Kb,
                                              const unsigned short* __restrict__ Vt,
                                              const float* __restrict__ bias_tab,
                                              const int* __restrict__ mask,
                                              unsigned short* __restrict__ Ob) {
  __shared__ unsigned short Ps[64][72];
  __shared__ float biasw[2112];           // biasw[kg - ql + 63], ql = local q row
  int qt = blockIdx.x, bh = blockIdx.y;
  int b = bh / NH, h = bh % NH;
  int tid = threadIdx.x, wave = tid >> 6, lane = tid & 63;
  int lr = lane & 15, lg = lane >> 4;
  int q0 = qt * 64;
  for (int i = tid; i < 2111; i += 256) biasw[i] = bias_tab[h * 4095 + (1984 - q0) + i];
  bf16x8 aq[2];
  int qw = q0 + wave * 16;
#pragma unroll
  for (int ks = 0; ks < 2; ++ks)
    aq[ks] = *(const bf16x8*)&Qb[(size_t)(b * NL + qw + lr) * ND + h * NDK + ks * 32 + lg * 8];
  const unsigned short* Kbase = Kb + (size_t)(b * NL) * ND + h * NDK;       // + key*768 + dk
  const unsigned short* Vbase = Vt + (size_t)(b * NH + h) * NDK * NL;       // + dk*2048 + key
  bf16x8 bk[8], bv[8];
  // prefetch K fragments for tile 0: bk[ks*4+ni] = K[key=ni*16+lr][dk=ks*32+lg*8..]
#pragma unroll
  for (int ks = 0; ks < 2; ++ks)
#pragma unroll
    for (int ni = 0; ni < 4; ++ni)
      bk[ks * 4 + ni] = *(const bf16x8*)&Kbase[(size_t)(ni * 16 + lr) * ND + ks * 32 + lg * 8];
  f32x4 accO[4] = {};
  float mst[4], lst[4];
#pragma unroll
  for (int r = 0; r < 4; ++r) { mst[r] = -1e30f; lst[r] = 0.f; }
  int boff = lr - wave * 16 - lg * 4 + 63;   // biasw idx = kt*64 + ni*16 + boff - r
  __syncthreads();                            // biasw ready
  for (int kt = 0; kt < NL / 64; ++kt) {
    // V fragments for this tile: bv[ks*4+ni] = V^T[dk=ni*16+lr][key=kt*64+ks*32+lg*8..]
#pragma unroll
    for (int ks = 0; ks < 2; ++ks)
#pragma unroll
      for (int ni = 0; ni < 4; ++ni)
        bv[ks * 4 + ni] = *(const bf16x8*)&Vbase[(size_t)(ni * 16 + lr) * NL + kt * 64 + ks * 32 + lg * 8];
    // scores: C-init = bias, then QK^T accumulates on top
    f32x4 s[4];
#pragma unroll
    for (int ni = 0; ni < 4; ++ni) {
#pragma unroll
      for (int r = 0; r < 4; ++r)
        s[ni][r] = biasw[kt * 64 + ni * 16 + boff - r];
      s[ni] = __builtin_amdgcn_mfma_f32_16x16x32_bf16(aq[0], bk[ni],     s[ni], 0, 0, 0);
      s[ni] = __builtin_amdgcn_mfma_f32_16x16x32_bf16(aq[1], bk[4 + ni], s[ni], 0, 0, 0);
    }
    // prefetch K for next tile (clamped reload on last iter; values unused)
    int ktn = (kt < NL / 64 - 1) ? kt + 1 : kt;
#pragma unroll
    for (int ks = 0; ks < 2; ++ks)
#pragma unroll
      for (int ni = 0; ni < 4; ++ni)
        bk[ks * 4 + ni] = *(const bf16x8*)&Kbase[(size_t)(ktn * 64 + ni * 16 + lr) * ND + ks * 32 + lg * 8];
    // padding mask
#pragma unroll
    for (int ni = 0; ni < 4; ++ni) {
      int mk = mask[b * NL + kt * 64 + ni * 16 + lr];
#pragma unroll
      for (int r = 0; r < 4; ++r)
        s[ni][r] = (mk == 0) ? -1e30f : s[ni][r];
    }
    // online softmax (row q = wave*16+lg*4+r lives in the 16-lane lr-group)
#pragma unroll
    for (int r = 0; r < 4; ++r) {
      float v = fmaxf(fmaxf(s[0][r], s[1][r]), fmaxf(s[2][r], s[3][r]));
      v = fmaxf(v, __shfl_xor(v, 1));
      v = fmaxf(v, __shfl_xor(v, 2));
      v = fmaxf(v, __shfl_xor(v, 4));
      v = fmaxf(v, __shfl_xor(v, 8));
      float mnew = fmaxf(mst[r], v);
      float sc = __expf(mst[r] - mnew);
      mst[r] = mnew;
      lst[r] *= sc;
#pragma unroll
      for (int ni = 0; ni < 4; ++ni) accO[ni][r] *= sc;
      float ps = 0.f;
#pragma unroll
      for (int ni = 0; ni < 4; ++ni) {
        float p = __expf(s[ni][r] - mnew);
        s[ni][r] = p;
        ps += p;
      }
      ps += __shfl_xor(ps, 1);
      ps += __shfl_xor(ps, 2);
      ps += __shfl_xor(ps, 4);
      ps += __shfl_xor(ps, 8);
      lst[r] += ps;
    }
#pragma unroll
    for (int ni = 0; ni < 4; ++ni)
#pragma unroll
      for (int r = 0; r < 4; ++r)
        Ps[wave * 16 + lg * 4 + r][ni * 16 + lr] = f2bf(s[ni][r]);
    __syncthreads();
    // O += P @ V  (V fragments already in regs)
#pragma unroll
    for (int ks = 0; ks < 2; ++ks) {
      bf16x8 ap = *(const bf16x8*)&Ps[wave * 16 + lr][ks * 32 + lg * 8];
#pragma unroll
      for (int ni = 0; ni < 4; ++ni)
        accO[ni] = __builtin_amdgcn_mfma_f32_16x16x32_bf16(ap, bv[ks * 4 + ni], accO[ni], 0, 0, 0);
    }
    __syncthreads();
  }
#pragma unroll
  for (int r = 0; r < 4; ++r) lst[r] = 1.0f / lst[r];
#pragma unroll
  for (int ni = 0; ni < 4; ++ni)
#pragma unroll
    for (int r = 0; r < 4; ++r) {
      int qg = qw + lg * 4 + r;
      int col = h * NDK + ni * 16 + lr;
      Ob[(size_t)(b * NL + qg) * ND + col] = f2bf(accO[ni][r] * lst[r]);
    }
}

extern "C" void kernel_launch(void* const* d_in, const int* in_sizes, int n_in,
                              void* d_out, int out_size, void* d_ws, size_t ws_size,
                              hipStream_t stream) {
  const float* query  = (const float*)d_in[0];
  const float* keyval = (const float*)d_in[1];
  const int*   mask   = (const int*)d_in[2];
  const float* Wq     = (const float*)d_in[3];
  const float* Wk     = (const float*)d_in[4];
  const float* Wv     = (const float*)d_in[5];
  const float* Wo     = (const float*)d_in[6];
  const float* rel    = (const float*)d_in[7];

  char* ws = (char*)d_ws;
  unsigned short* q_bf  = (unsigned short*)(ws);              // 4096x768 bf16 (query*0.125)
  unsigned short* kv_bf = (unsigned short*)(ws + 6291456);
  unsigned short* Wq_t  = (unsigned short*)(ws + 12582912);   // [N][K] bf16
  unsigned short* Wk_t  = (unsigned short*)(ws + 13762560);
  unsigned short* Wv_t  = (unsigned short*)(ws + 14942208);
  unsigned short* Wo_t  = (unsigned short*)(ws + 16121856);
  unsigned short* Qb    = (unsigned short*)(ws + 17301504);   // [B,L,H,DK]
  unsigned short* Kb    = (unsigned short*)(ws + 23592960);
  unsigned short* Vt    = (unsigned short*)(ws + 29884416);   // [B,768,L] (== [B,H,DK,L])
  unsigned short* Ob    = (unsigned short*)(ws + 36175872);   // [B,L,H*DK]
  float* bias_tab       = (float*)(ws + 42467328);            // [H][4095]

  k_bias<<<dim3(192), dim3(256), 0, stream>>>(rel, bias_tab);
  k_conv<<<dim3(3072), dim3(256), 0, stream>>>(query, q_bf, 786432, 0.125f);
  k_conv<<<dim3(3072), dim3(256), 0, stream>>>(keyval, kv_bf, 786432, 1.0f);
  k_wt<<<dim3(24, 24, 4), dim3(32, 8), 0, stream>>>(Wq, Wk, Wv, Wo, Wq_t, Wk_t, Wv_t, Wo_t);
  k_gemm<<<dim3(64, 12), dim3(256), 0, stream>>>(q_bf,  Wq_t, (void*)Qb, NM, ND, ND, 0);
  k_gemm<<<dim3(64, 12), dim3(256), 0, stream>>>(kv_bf, Wk_t, (void*)Kb, NM, ND, ND, 0);
  k_gemm<<<dim3(64, 12), dim3(256), 0, stream>>>(kv_bf, Wv_t, (void*)Vt, NM, ND, ND, 2);
  k_attn<<<dim3(32, 24), dim3(256), 0, stream>>>(Qb, Kb, Vt, bias_tab, mask, Ob);
  k_gemm<<<dim3(64, 12), dim3(256), 0, stream>>>(Ob, Wo_t, d_out, NM, ND, ND, 1);
}

// Round 4
// 171.530 us; speedup vs baseline: 1.5438x; 1.5438x over previous
//
#include <hip/hip_runtime.h>
#include <stdint.h>

typedef __attribute__((ext_vector_type(8))) short bf16x8;
typedef __attribute__((ext_vector_type(4))) float f32x4;
typedef __attribute__((ext_vector_type(4))) unsigned int u32x4;

#define NB 2
#define NL 2048
#define ND 768
#define NH 12
#define NDK 64
#define NM 4096   // NB*NL

__device__ __forceinline__ unsigned short f2bf(float f) {
  unsigned u = __builtin_bit_cast(unsigned, f);
  u += 0x7FFFu + ((u >> 16) & 1u);          // RNE
  return (unsigned short)(u >> 16);
}

__device__ __forceinline__ void gl_lds16(const unsigned short* g, unsigned short* l) {
  __builtin_amdgcn_global_load_lds((const __attribute__((address_space(1))) void*)g,
                                   (__attribute__((address_space(3))) void*)l, 16, 0, 0);
}

// ---- T5 relative-position bias table: bias_tab[h][d+2047], d = k - q ----
__global__ void k_bias(const float* __restrict__ rel_emb, float* __restrict__ bias_tab) {
  int idx = blockIdx.x * 256 + threadIdx.x;
  if (idx >= 4095 * NH) return;
  int h = idx % NH;
  int di = idx / NH;
  int rel = di - 2047;          // rel = k - q
  int n = -rel;
  int ret = 0;
  if (n < 0) { ret = 16; n = -n; }
  int b;
  if (n < 8) {
    b = ret + n;
  } else {
    int v = (n >= 91) ? 7 : (n >= 64) ? 6 : (n >= 46) ? 5 : (n >= 32) ? 4
          : (n >= 23) ? 3 : (n >= 16) ? 2 : (n >= 12) ? 1 : 0;
    b = ret + 8 + v;
  }
  bias_tab[h * 4095 + di] = rel_emb[b * NH + h];
}

// ---- fp32 -> bf16 (vectorized), optional scale ----
__global__ void k_conv(const float* __restrict__ src, unsigned short* __restrict__ dst,
                       int n4, float scale) {
  int i = blockIdx.x * 256 + threadIdx.x;
  if (i >= n4) return;
  float4 v = ((const float4*)src)[i];
  ushort4 o;
  o.x = f2bf(v.x * scale);
  o.y = f2bf(v.y * scale);
  o.z = f2bf(v.z * scale);
  o.w = f2bf(v.w * scale);
  ((ushort4*)dst)[i] = o;
}

// ---- W [K][N] fp32 -> Wt [N][K] bf16 (768x768), 4 matrices selected by z ----
__global__ void k_wt(const float* __restrict__ w0, const float* __restrict__ w1,
                     const float* __restrict__ w2, const float* __restrict__ w3,
                     unsigned short* __restrict__ o0, unsigned short* __restrict__ o1,
                     unsigned short* __restrict__ o2, unsigned short* __restrict__ o3) {
  const float* w = (blockIdx.z == 0) ? w0 : (blockIdx.z == 1) ? w1 : (blockIdx.z == 2) ? w2 : w3;
  unsigned short* o = (blockIdx.z == 0) ? o0 : (blockIdx.z == 1) ? o1 : (blockIdx.z == 2) ? o2 : o3;
  __shared__ float t[32][33];
  int bx = blockIdx.x * 32, by = blockIdx.y * 32;
  int tx = threadIdx.x, ty = threadIdx.y;
  for (int r = 0; r < 32; r += 8)
    t[ty + r][tx] = w[(by + ty + r) * ND + bx + tx];
  __syncthreads();
  for (int r = 0; r < 32; r += 8)
    o[(bx + ty + r) * ND + by + tx] = f2bf(t[tx][ty + r]);
}

// ---- bf16 MFMA GEMM: C[M,N] = A[M,K]*Bt[N,K]^T. 64x64 tile, BK=64, dbuf LDS,
// global_load_lds w16, XOR-swizzled (chunk ^= row&7, inverse-swz global source).
// mode 0: bf16 row-major out; 1: fp32 row-major out; 2: bf16 Vt out [B][768][L]
__global__ __launch_bounds__(256) void k_gemm(const unsigned short* __restrict__ A,
                                              const unsigned short* __restrict__ Bt,
                                              void* __restrict__ Cout,
                                              int Msz, int Nsz, int Ksz, int mode) {
  __shared__ unsigned short As[2][4096];   // [64 rows][64 k] linear, 8 KB each
  __shared__ unsigned short Bs[2][4096];
  int tid = threadIdx.x;
  int wave = tid >> 6, lane = tid & 63;
  int lr = lane & 15, lg = lane >> 4;
  int m0 = blockIdx.x * 64, n0 = blockIdx.y * 64;
  int wm = (wave >> 1) * 32, wn = (wave & 1) * 32;
  int srow = tid >> 3, spc = tid & 7;
  int sg = spc ^ (srow & 7);                       // inverse swizzle on global source
  const unsigned short* Ag0 = A  + (size_t)(m0 + srow) * Ksz + sg * 8;
  const unsigned short* Ag1 = A  + (size_t)(m0 + 32 + srow) * Ksz + sg * 8;
  const unsigned short* Bg0 = Bt + (size_t)(n0 + srow) * Ksz + sg * 8;
  const unsigned short* Bg1 = Bt + (size_t)(n0 + 32 + srow) * Ksz + sg * 8;
  f32x4 acc[2][2] = {};
  const int KT = Ksz >> 6;
  gl_lds16(Ag0, &As[0][tid * 8]);
  gl_lds16(Ag1, &As[0][2048 + tid * 8]);
  gl_lds16(Bg0, &Bs[0][tid * 8]);
  gl_lds16(Bg1, &Bs[0][2048 + tid * 8]);
  __syncthreads();
  int cur = 0;
  for (int t = 0; t < KT; ++t) {
    if (t + 1 < KT) {
      int k0 = (t + 1) << 6;
      gl_lds16(Ag0 + k0, &As[cur ^ 1][tid * 8]);
      gl_lds16(Ag1 + k0, &As[cur ^ 1][2048 + tid * 8]);
      gl_lds16(Bg0 + k0, &Bs[cur ^ 1][tid * 8]);
      gl_lds16(Bg1 + k0, &Bs[cur ^ 1][2048 + tid * 8]);
    }
#pragma unroll
    for (int ks = 0; ks < 2; ++ks) {
      bf16x8 af[2], bfr[2];
#pragma unroll
      for (int i = 0; i < 2; ++i) {
        int ar = wm + i * 16 + lr;
        af[i] = *(const bf16x8*)&As[cur][ar * 64 + (((ks * 4 + lg) ^ (ar & 7)) * 8)];
        int br = wn + i * 16 + lr;
        bfr[i] = *(const bf16x8*)&Bs[cur][br * 64 + (((ks * 4 + lg) ^ (br & 7)) * 8)];
      }
#pragma unroll
      for (int mi = 0; mi < 2; ++mi)
#pragma unroll
        for (int ni = 0; ni < 2; ++ni)
          acc[mi][ni] = __builtin_amdgcn_mfma_f32_16x16x32_bf16(af[mi], bfr[ni], acc[mi][ni], 0, 0, 0);
    }
    __syncthreads();   // drains vmcnt (prefetch done) + protects buffer swap
    cur ^= 1;
  }
#pragma unroll
  for (int mi = 0; mi < 2; ++mi)
#pragma unroll
    for (int ni = 0; ni < 2; ++ni)
#pragma unroll
      for (int r = 0; r < 4; ++r) {
        int row = m0 + wm + mi * 16 + lg * 4 + r;   // C/D: col=lane&15, row=(lane>>4)*4+reg
        int col = n0 + wn + ni * 16 + lr;
        float v = acc[mi][ni][r];
        if (mode == 0) {
          ((unsigned short*)Cout)[(size_t)row * Nsz + col] = f2bf(v);
        } else if (mode == 1) {
          ((float*)Cout)[(size_t)row * Nsz + col] = v;
        } else {
          int bb = row >> 11, l = row & 2047;       // Vt[(b*768+col)][l]
          ((unsigned short*)Cout)[(((size_t)bb * ND + col) << 11) + l] = f2bf(v);
        }
      }
}

// ---- fused flash attention: one (b,h,64-row q-tile) per block, 4 waves x 16 rows.
// K/V staged to LDS via global_load_lds (linear dest, inverse-swz source, swz read),
// double-buffered; stage(t+1) overlaps QK^T+softmax(t). Bias folded as MFMA C-init.
// 2 barriers/iter. LDS = 16K K + 16K V + 9.2K Ps + 8.4K bias = 50.4 KB -> 3 blk/CU.
__global__ __launch_bounds__(256) void k_attn(const unsigned short* __restrict__ Qb,
                                              const unsigned short* __restrict__ Kb,
                                              const unsigned short* __restrict__ Vt,
                                              const float* __restrict__ bias_tab,
                                              const int* __restrict__ mask,
                                              unsigned short* __restrict__ Ob) {
  __shared__ unsigned short Ks[2][4096];   // [64 keys][64 dk] linear + XOR swizzle
  __shared__ unsigned short Vs[2][4096];   // [64 dk][64 keys] linear + XOR swizzle
  __shared__ unsigned short Ps[64][72];
  __shared__ float biasw[2112];            // biasw[kg - ql + 63], ql = local q row
  int qt = blockIdx.x, bh = blockIdx.y;
  int b = bh / NH, h = bh % NH;
  int tid = threadIdx.x, wave = tid >> 6, lane = tid & 63;
  int lr = lane & 15, lg = lane >> 4;
  int q0 = qt * 64;
  for (int i = tid; i < 2111; i += 256) biasw[i] = bias_tab[h * 4095 + (1984 - q0) + i];
  const unsigned short* Kbase = Kb + (size_t)(b * NL) * ND + h * NDK;       // + key*768 + dk
  const unsigned short* Vbase = Vt + (size_t)(b * NH + h) * NDK * NL;       // + dk*2048 + key
  // staging map: LDS row = tid>>3 (+32 for 2nd shot), chunk spc = tid&7, dest linear tid*16B
  int srow = tid >> 3, spc = tid & 7;
  int sg = spc ^ (srow & 7);
  const unsigned short* Kg0 = Kbase + (size_t)srow * ND + sg * 8;        // + kt*64*ND
  const unsigned short* Kg1 = Kbase + (size_t)(32 + srow) * ND + sg * 8;
  const unsigned short* Vg0 = Vbase + (size_t)srow * NL + sg * 8;        // + kt*64
  const unsigned short* Vg1 = Vbase + (size_t)(32 + srow) * NL + sg * 8;
  bf16x8 aq[2];
  int qw = q0 + wave * 16;
#pragma unroll
  for (int ks = 0; ks < 2; ++ks)
    aq[ks] = *(const bf16x8*)&Qb[(size_t)(b * NL + qw + lr) * ND + h * NDK + ks * 32 + lg * 8];
  f32x4 accO[4] = {};
  float mst[4], lst[4];
#pragma unroll
  for (int r = 0; r < 4; ++r) { mst[r] = -1e30f; lst[r] = 0.f; }
  int boff = lr - wave * 16 - lg * 4 + 63;   // biasw idx = kt*64 + ni*16 + boff - r
  // prologue: stage tile 0
  gl_lds16(Kg0, &Ks[0][tid * 8]);
  gl_lds16(Kg1, &Ks[0][2048 + tid * 8]);
  gl_lds16(Vg0, &Vs[0][tid * 8]);
  gl_lds16(Vg1, &Vs[0][2048 + tid * 8]);
  __syncthreads();                           // biasw + tile 0 ready
  int cur = 0;
  const int NT = NL / 64;
  for (int kt = 0; kt < NT; ++kt) {
    if (kt + 1 < NT) {                       // stage next tile; completes at barrier below
      size_t ko = (size_t)(kt + 1) * 64;
      gl_lds16(Kg0 + ko * ND, &Ks[cur ^ 1][tid * 8]);
      gl_lds16(Kg1 + ko * ND, &Ks[cur ^ 1][2048 + tid * 8]);
      gl_lds16(Vg0 + ko, &Vs[cur ^ 1][tid * 8]);
      gl_lds16(Vg1 + ko, &Vs[cur ^ 1][2048 + tid * 8]);
    }
    // scores: C-init = bias, then QK^T accumulates on top
    f32x4 s[4];
#pragma unroll
    for (int ni = 0; ni < 4; ++ni) {
#pragma unroll
      for (int r = 0; r < 4; ++r)
        s[ni][r] = biasw[kt * 64 + ni * 16 + boff - r];
      int kr = ni * 16 + lr;
      bf16x8 bk0 = *(const bf16x8*)&Ks[cur][kr * 64 + ((lg ^ (kr & 7)) * 8)];
      bf16x8 bk1 = *(const bf16x8*)&Ks[cur][kr * 64 + (((4 + lg) ^ (kr & 7)) * 8)];
      s[ni] = __builtin_amdgcn_mfma_f32_16x16x32_bf16(aq[0], bk0, s[ni], 0, 0, 0);
      s[ni] = __builtin_amdgcn_mfma_f32_16x16x32_bf16(aq[1], bk1, s[ni], 0, 0, 0);
    }
    // padding mask
#pragma unroll
    for (int ni = 0; ni < 4; ++ni) {
      int mk = mask[b * NL + kt * 64 + ni * 16 + lr];
#pragma unroll
      for (int r = 0; r < 4; ++r)
        s[ni][r] = (mk == 0) ? -1e30f : s[ni][r];
    }
    // online softmax (row q = wave*16+lg*4+r lives in the 16-lane lr-group)
#pragma unroll
    for (int r = 0; r < 4; ++r) {
      float v = fmaxf(fmaxf(s[0][r], s[1][r]), fmaxf(s[2][r], s[3][r]));
      v = fmaxf(v, __shfl_xor(v, 1));
      v = fmaxf(v, __shfl_xor(v, 2));
      v = fmaxf(v, __shfl_xor(v, 4));
      v = fmaxf(v, __shfl_xor(v, 8));
      float mnew = fmaxf(mst[r], v);
      float sc = __expf(mst[r] - mnew);
      mst[r] = mnew;
      lst[r] *= sc;
#pragma unroll
      for (int ni = 0; ni < 4; ++ni) accO[ni][r] *= sc;
      float ps = 0.f;
#pragma unroll
      for (int ni = 0; ni < 4; ++ni) {
        float p = __expf(s[ni][r] - mnew);
        s[ni][r] = p;
        ps += p;
      }
      ps += __shfl_xor(ps, 1);
      ps += __shfl_xor(ps, 2);
      ps += __shfl_xor(ps, 4);
      ps += __shfl_xor(ps, 8);
      lst[r] += ps;
    }
#pragma unroll
    for (int ni = 0; ni < 4; ++ni)
#pragma unroll
      for (int r = 0; r < 4; ++r)
        Ps[wave * 16 + lg * 4 + r][ni * 16 + lr] = f2bf(s[ni][r]);
    __syncthreads();   // Ps visible; also drains vmcnt -> next tile staged
    // O += P @ V
#pragma unroll
    for (int ks = 0; ks < 2; ++ks) {
      bf16x8 ap = *(const bf16x8*)&Ps[wave * 16 + lr][ks * 32 + lg * 8];
#pragma unroll
      for (int ni = 0; ni < 4; ++ni) {
        int vr = ni * 16 + lr;
        bf16x8 bv = *(const bf16x8*)&Vs[cur][vr * 64 + (((ks * 4 + lg) ^ (vr & 7)) * 8)];
        accO[ni] = __builtin_amdgcn_mfma_f32_16x16x32_bf16(ap, bv, accO[ni], 0, 0, 0);
      }
    }
    __syncthreads();   // Ps + K/V[cur] reads done -> next iter may overwrite
    cur ^= 1;
  }
#pragma unroll
  for (int r = 0; r < 4; ++r) lst[r] = 1.0f / lst[r];
#pragma unroll
  for (int ni = 0; ni < 4; ++ni)
#pragma unroll
    for (int r = 0; r < 4; ++r) {
      int qg = qw + lg * 4 + r;
      int col = h * NDK + ni * 16 + lr;
      Ob[(size_t)(b * NL + qg) * ND + col] = f2bf(accO[ni][r] * lst[r]);
    }
}

extern "C" void kernel_launch(void* const* d_in, const int* in_sizes, int n_in,
                              void* d_out, int out_size, void* d_ws, size_t ws_size,
                              hipStream_t stream) {
  const float* query  = (const float*)d_in[0];
  const float* keyval = (const float*)d_in[1];
  const int*   mask   = (const int*)d_in[2];
  const float* Wq     = (const float*)d_in[3];
  const float* Wk     = (const float*)d_in[4];
  const float* Wv     = (const float*)d_in[5];
  const float* Wo     = (const float*)d_in[6];
  const float* rel    = (const float*)d_in[7];

  char* ws = (char*)d_ws;
  unsigned short* q_bf  = (unsigned short*)(ws);              // 4096x768 bf16 (query*0.125)
  unsigned short* kv_bf = (unsigned short*)(ws + 6291456);
  unsigned short* Wq_t  = (unsigned short*)(ws + 12582912);   // [N][K] bf16
  unsigned short* Wk_t  = (unsigned short*)(ws + 13762560);
  unsigned short* Wv_t  = (unsigned short*)(ws + 14942208);
  unsigned short* Wo_t  = (unsigned short*)(ws + 16121856);
  unsigned short* Qb    = (unsigned short*)(ws + 17301504);   // [B,L,H,DK]
  unsigned short* Kb    = (unsigned short*)(ws + 23592960);
  unsigned short* Vt    = (unsigned short*)(ws + 29884416);   // [B,768,L] (== [B,H,DK,L])
  unsigned short* Ob    = (unsigned short*)(ws + 36175872);   // [B,L,H*DK]
  float* bias_tab       = (float*)(ws + 42467328);            // [H][4095]

  k_bias<<<dim3(192), dim3(256), 0, stream>>>(rel, bias_tab);
  k_conv<<<dim3(3072), dim3(256), 0, stream>>>(query, q_bf, 786432, 0.125f);
  k_conv<<<dim3(3072), dim3(256), 0, stream>>>(keyval, kv_bf, 786432, 1.0f);
  k_wt<<<dim3(24, 24, 4), dim3(32, 8), 0, stream>>>(Wq, Wk, Wv, Wo, Wq_t, Wk_t, Wv_t, Wo_t);
  k_gemm<<<dim3(64, 12), dim3(256), 0, stream>>>(q_bf,  Wq_t, (void*)Qb, NM, ND, ND, 0);
  k_gemm<<<dim3(64, 12), dim3(256), 0, stream>>>(kv_bf, Wk_t, (void*)Kb, NM, ND, ND, 0);
  k_gemm<<<dim3(64, 12), dim3(256), 0, stream>>>(kv_bf, Wv_t, (void*)Vt, NM, ND, ND, 2);
  k_attn<<<dim3(32, 24), dim3(256), 0, stream>>>(Qb, Kb, Vt, bias_tab, mask, Ob);
  k_gemm<<<dim3(64, 12), dim3(256), 0, stream>>>(Ob, Wo_t, d_out, NM, ND, ND, 1);
}

// Round 5
// 129.897 us; speedup vs baseline: 2.0385x; 1.3205x over previous
//
#include <hip/hip_runtime.h>
#include <stdint.h>

typedef __attribute__((ext_vector_type(8))) short bf16x8;
typedef __attribute__((ext_vector_type(4))) float f32x4;
typedef __attribute__((ext_vector_type(4))) unsigned int u32x4;

#define NB 2
#define NL 2048
#define ND 768
#define NH 12
#define NDK 64
#define NM 4096   // NB*NL

__device__ __forceinline__ unsigned short f2bf(float f) {
  unsigned u = __builtin_bit_cast(unsigned, f);
  u += 0x7FFFu + ((u >> 16) & 1u);          // RNE
  return (unsigned short)(u >> 16);
}

__device__ __forceinline__ void gl_lds16(const unsigned short* g, unsigned short* l) {
  __builtin_amdgcn_global_load_lds((const __attribute__((address_space(1))) void*)g,
                                   (__attribute__((address_space(3))) void*)l, 16, 0, 0);
}

// ---- T5 relative-position bias table: bias_tab[h][d+2047], d = k - q ----
__global__ void k_bias(const float* __restrict__ rel_emb, float* __restrict__ bias_tab) {
  int idx = blockIdx.x * 256 + threadIdx.x;
  if (idx >= 4095 * NH) return;
  int h = idx % NH;
  int di = idx / NH;
  int rel = di - 2047;          // rel = k - q
  int n = -rel;
  int ret = 0;
  if (n < 0) { ret = 16; n = -n; }
  int b;
  if (n < 8) {
    b = ret + n;
  } else {
    int v = (n >= 91) ? 7 : (n >= 64) ? 6 : (n >= 46) ? 5 : (n >= 32) ? 4
          : (n >= 23) ? 3 : (n >= 16) ? 2 : (n >= 12) ? 1 : 0;
    b = ret + 8 + v;
  }
  bias_tab[h * 4095 + di] = rel_emb[b * NH + h];
}

// ---- mask -> additive float array + per-batch all-ones flag ----
__global__ void k_maskadd(const int* __restrict__ mask, float* __restrict__ maskadd,
                          int* __restrict__ maskall) {
  __shared__ int red[256];
  int b = blockIdx.x;
  int t = threadIdx.x;
  int acc = 1;
  for (int i = t; i < NL; i += 256) {
    int m = mask[b * NL + i];
    maskadd[b * NL + i] = m ? 0.0f : -1e30f;
    acc &= (m != 0) ? 1 : 0;
  }
  red[t] = acc;
  __syncthreads();
  for (int s2 = 128; s2 > 0; s2 >>= 1) {
    if (t < s2) red[t] &= red[t + s2];
    __syncthreads();
  }
  if (t == 0) maskall[b] = red[0];
}

// ---- fp32 -> bf16 (vectorized), optional scale ----
__global__ void k_conv(const float* __restrict__ src, unsigned short* __restrict__ dst,
                       int n4, float scale) {
  int i = blockIdx.x * 256 + threadIdx.x;
  if (i >= n4) return;
  float4 v = ((const float4*)src)[i];
  ushort4 o;
  o.x = f2bf(v.x * scale);
  o.y = f2bf(v.y * scale);
  o.z = f2bf(v.z * scale);
  o.w = f2bf(v.w * scale);
  ((ushort4*)dst)[i] = o;
}

// ---- W [K][N] fp32 -> Wt [N][K] bf16 (768x768), 4 matrices selected by z ----
__global__ void k_wt(const float* __restrict__ w0, const float* __restrict__ w1,
                     const float* __restrict__ w2, const float* __restrict__ w3,
                     unsigned short* __restrict__ o0, unsigned short* __restrict__ o1,
                     unsigned short* __restrict__ o2, unsigned short* __restrict__ o3) {
  const float* w = (blockIdx.z == 0) ? w0 : (blockIdx.z == 1) ? w1 : (blockIdx.z == 2) ? w2 : w3;
  unsigned short* o = (blockIdx.z == 0) ? o0 : (blockIdx.z == 1) ? o1 : (blockIdx.z == 2) ? o2 : o3;
  __shared__ float t[32][33];
  int bx = blockIdx.x * 32, by = blockIdx.y * 32;
  int tx = threadIdx.x, ty = threadIdx.y;
  for (int r = 0; r < 32; r += 8)
    t[ty + r][tx] = w[(by + ty + r) * ND + bx + tx];
  __syncthreads();
  for (int r = 0; r < 32; r += 8)
    o[(bx + ty + r) * ND + by + tx] = f2bf(t[tx][ty + r]);
}

// ---- bf16 MFMA GEMM: C[M,N] = A[M,K]*Bt[N,K]^T. 64x64 tile, BK=64, dbuf LDS,
// global_load_lds w16, XOR-swizzled (chunk ^= row&7, inverse-swz global source).
// mode 0: bf16 row-major out; 1: fp32 row-major out; 2: bf16 Vt out [B][768][L]
__global__ __launch_bounds__(256) void k_gemm(const unsigned short* __restrict__ A,
                                              const unsigned short* __restrict__ Bt,
                                              void* __restrict__ Cout,
                                              int Msz, int Nsz, int Ksz, int mode) {
  __shared__ unsigned short As[2][4096];   // [64 rows][64 k] linear, 8 KB each
  __shared__ unsigned short Bs[2][4096];
  int tid = threadIdx.x;
  int wave = tid >> 6, lane = tid & 63;
  int lr = lane & 15, lg = lane >> 4;
  int m0 = blockIdx.x * 64, n0 = blockIdx.y * 64;
  int wm = (wave >> 1) * 32, wn = (wave & 1) * 32;
  int srow = tid >> 3, spc = tid & 7;
  int sg = spc ^ (srow & 7);                       // inverse swizzle on global source
  const unsigned short* Ag0 = A  + (size_t)(m0 + srow) * Ksz + sg * 8;
  const unsigned short* Ag1 = A  + (size_t)(m0 + 32 + srow) * Ksz + sg * 8;
  const unsigned short* Bg0 = Bt + (size_t)(n0 + srow) * Ksz + sg * 8;
  const unsigned short* Bg1 = Bt + (size_t)(n0 + 32 + srow) * Ksz + sg * 8;
  f32x4 acc[2][2] = {};
  const int KT = Ksz >> 6;
  gl_lds16(Ag0, &As[0][tid * 8]);
  gl_lds16(Ag1, &As[0][2048 + tid * 8]);
  gl_lds16(Bg0, &Bs[0][tid * 8]);
  gl_lds16(Bg1, &Bs[0][2048 + tid * 8]);
  __syncthreads();
  int cur = 0;
  for (int t = 0; t < KT; ++t) {
    if (t + 1 < KT) {
      int k0 = (t + 1) << 6;
      gl_lds16(Ag0 + k0, &As[cur ^ 1][tid * 8]);
      gl_lds16(Ag1 + k0, &As[cur ^ 1][2048 + tid * 8]);
      gl_lds16(Bg0 + k0, &Bs[cur ^ 1][tid * 8]);
      gl_lds16(Bg1 + k0, &Bs[cur ^ 1][2048 + tid * 8]);
    }
#pragma unroll
    for (int ks = 0; ks < 2; ++ks) {
      bf16x8 af[2], bfr[2];
#pragma unroll
      for (int i = 0; i < 2; ++i) {
        int ar = wm + i * 16 + lr;
        af[i] = *(const bf16x8*)&As[cur][ar * 64 + (((ks * 4 + lg) ^ (ar & 7)) * 8)];
        int br = wn + i * 16 + lr;
        bfr[i] = *(const bf16x8*)&Bs[cur][br * 64 + (((ks * 4 + lg) ^ (br & 7)) * 8)];
      }
#pragma unroll
      for (int mi = 0; mi < 2; ++mi)
#pragma unroll
        for (int ni = 0; ni < 2; ++ni)
          acc[mi][ni] = __builtin_amdgcn_mfma_f32_16x16x32_bf16(af[mi], bfr[ni], acc[mi][ni], 0, 0, 0);
    }
    __syncthreads();   // drains vmcnt (prefetch done) + protects buffer swap
    cur ^= 1;
  }
#pragma unroll
  for (int mi = 0; mi < 2; ++mi)
#pragma unroll
    for (int ni = 0; ni < 2; ++ni)
#pragma unroll
      for (int r = 0; r < 4; ++r) {
        int row = m0 + wm + mi * 16 + lg * 4 + r;   // C/D: col=lane&15, row=(lane>>4)*4+reg
        int col = n0 + wn + ni * 16 + lr;
        float v = acc[mi][ni][r];
        if (mode == 0) {
          ((unsigned short*)Cout)[(size_t)row * Nsz + col] = f2bf(v);
        } else if (mode == 1) {
          ((float*)Cout)[(size_t)row * Nsz + col] = v;
        } else {
          int bb = row >> 11, l = row & 2047;       // Vt[(b*768+col)][l]
          ((unsigned short*)Cout)[(((size_t)bb * ND + col) << 11) + l] = f2bf(v);
        }
      }
}

// ---- fused flash attention, swapped-QK^T: one (b,h,64-q-tile) per block, 4 waves.
// s = mfma(K, Q): each lane owns row q=lr. K tile staged with permuted key order
// (phys 16ni+4lg+r holds logical (ni&1)*32+lg*8+(ni>>1)*4+r) so exp'd P values are
// directly the PV A-fragment (in-lane pack, no LDS round-trip). 1 barrier/iter.
__global__ __launch_bounds__(256, 3) void k_attn(const unsigned short* __restrict__ Qb,
                                                 const unsigned short* __restrict__ Kb,
                                                 const unsigned short* __restrict__ Vt,
                                                 const float* __restrict__ bias_tab,
                                                 const float* __restrict__ maskadd,
                                                 const int* __restrict__ maskall,
                                                 unsigned short* __restrict__ Ob) {
  __shared__ unsigned short Ks[2][4096];   // [64 phys keys][64 dk], XOR-swizzled chunks
  __shared__ unsigned short Vs[2][4096];   // [64 dk][64 keys natural], XOR-swizzled
  __shared__ float biasw[2112];            // biasw[kg - ql + 63]
  int qt = blockIdx.x, bh = blockIdx.y;
  int b = bh / NH, h = bh % NH;
  int tid = threadIdx.x, wave = tid >> 6, lane = tid & 63;
  int lr = lane & 15, lg = lane >> 4;
  int q0 = qt * 64;
  for (int i = tid; i < 2111; i += 256) biasw[i] = bias_tab[h * 4095 + (1984 - q0) + i];
  const unsigned short* Kbase = Kb + (size_t)(b * NL) * ND + h * NDK;   // + key*768 + dk
  const unsigned short* Vbase = Vt + (size_t)(b * NH + h) * NDK * NL;   // + dk*2048 + key
  int srow = tid >> 3, spc = tid & 7;
  int sg = spc ^ (srow & 7);
  // key permutation: phys row srow (ni=srow>>4 in {0,1}) stores logical key l0; +32 -> l0+4
  int l0 = (srow >> 4) * 32 + ((srow >> 2) & 3) * 8 + (srow & 3);
  const unsigned short* Kg0 = Kbase + (size_t)l0 * ND + sg * 8;
  const unsigned short* Kg1 = Kbase + (size_t)(l0 + 4) * ND + sg * 8;
  const unsigned short* Vg0 = Vbase + (size_t)srow * NL + sg * 8;
  const unsigned short* Vg1 = Vbase + (size_t)(32 + srow) * NL + sg * 8;
  bf16x8 aq[2];
  int qw = q0 + wave * 16;
#pragma unroll
  for (int ks = 0; ks < 2; ++ks)
    aq[ks] = *(const bf16x8*)&Qb[(size_t)(b * NL + qw + lr) * ND + h * NDK + ks * 32 + lg * 8];
  const float* cbase = maskadd + b * NL;
  int nomask = __builtin_amdgcn_readfirstlane(maskall[b]);
  f32x4 accO[4] = {};
  float mst = -1e30f, lst = 0.f;
  int bconst = lg * 8 - (wave * 16 + lr) + 63;
  int src0 = (lane & 48) | ((lane >> 2) & 12);   // shfl src base: row 4*lg+r lives at lr=4lg+r
  gl_lds16(Kg0, &Ks[0][tid * 8]);
  gl_lds16(Kg1, &Ks[0][2048 + tid * 8]);
  gl_lds16(Vg0, &Vs[0][tid * 8]);
  gl_lds16(Vg1, &Vs[0][2048 + tid * 8]);
  __syncthreads();
  int cur = 0;
  const int NT = NL / 64;
  for (int kt = 0; kt < NT; ++kt) {
    // mask loads FIRST (issued before gl_lds so their waitcnt doesn't drain staging)
    float4 cv[2][2];
    if (!nomask) {
#pragma unroll
      for (int hf = 0; hf < 2; ++hf)
#pragma unroll
        for (int qd = 0; qd < 2; ++qd)
          cv[hf][qd] = *(const float4*)&cbase[kt * 64 + hf * 32 + lg * 8 + qd * 4];
    }
    if (kt + 1 < NT) {
      size_t kok = (size_t)(kt + 1) * 64 * ND;
      size_t kov = (size_t)(kt + 1) * 64;
      gl_lds16(Kg0 + kok, &Ks[cur ^ 1][tid * 8]);
      gl_lds16(Kg1 + kok, &Ks[cur ^ 1][2048 + tid * 8]);
      gl_lds16(Vg0 + kov, &Vs[cur ^ 1][tid * 8]);
      gl_lds16(Vg1 + kov, &Vs[cur ^ 1][2048 + tid * 8]);
    }
    // scores C-init = bias (+ mask additive); logical k = (ni&1)*32 + lg*8 + (ni>>1)*4 + r
    f32x4 s[4];
#pragma unroll
    for (int ni = 0; ni < 4; ++ni)
#pragma unroll
      for (int r = 0; r < 4; ++r)
        s[ni][r] = biasw[kt * 64 + (ni & 1) * 32 + (ni >> 1) * 4 + r + bconst];
    if (!nomask) {
#pragma unroll
      for (int ni = 0; ni < 4; ++ni)
#pragma unroll
        for (int r = 0; r < 4; ++r)
          s[ni][r] += ((const float*)&cv[ni & 1][ni >> 1])[r];
    }
    // S^T = K · Q^T : C col = q (lr), C row = phys key 4lg+r within subtile ni
    __builtin_amdgcn_s_setprio(1);
#pragma unroll
    for (int ni = 0; ni < 4; ++ni) {
      int kr = ni * 16 + lr;
      bf16x8 bk0 = *(const bf16x8*)&Ks[cur][kr * 64 + ((lg ^ (lr & 7)) * 8)];
      bf16x8 bk1 = *(const bf16x8*)&Ks[cur][kr * 64 + (((4 + lg) ^ (lr & 7)) * 8)];
      s[ni] = __builtin_amdgcn_mfma_f32_16x16x32_bf16(bk0, aq[0], s[ni], 0, 0, 0);
      s[ni] = __builtin_amdgcn_mfma_f32_16x16x32_bf16(bk1, aq[1], s[ni], 0, 0, 0);
    }
    __builtin_amdgcn_s_setprio(0);
    // in-register online softmax: lane owns 16 of 64 keys of row q=lr
    f32x4 t0, t1;
#pragma unroll
    for (int r = 0; r < 4; ++r) t0[r] = fmaxf(s[0][r], s[1][r]);
#pragma unroll
    for (int r = 0; r < 4; ++r) t1[r] = fmaxf(s[2][r], s[3][r]);
#pragma unroll
    for (int r = 0; r < 4; ++r) t0[r] = fmaxf(t0[r], t1[r]);
    float pmax = fmaxf(fmaxf(t0[0], t0[1]), fmaxf(t0[2], t0[3]));
    pmax = fmaxf(pmax, __shfl_xor(pmax, 16));
    pmax = fmaxf(pmax, __shfl_xor(pmax, 32));
    float mnew = fmaxf(mst, pmax);
    float sc = __expf(mst - mnew);
    mst = mnew;
    lst *= sc;
    float scB[4];
#pragma unroll
    for (int r = 0; r < 4; ++r) scB[r] = __shfl(sc, src0 | r);
#pragma unroll
    for (int ni = 0; ni < 4; ++ni)
#pragma unroll
      for (int r = 0; r < 4; ++r) accO[ni][r] *= scB[r];
#pragma unroll
    for (int ni = 0; ni < 4; ++ni)
#pragma unroll
      for (int r = 0; r < 4; ++r) s[ni][r] = __expf(s[ni][r] - mnew);
    float ps = 0.f;
#pragma unroll
    for (int r = 0; r < 4; ++r) ps += (s[0][r] + s[1][r]) + (s[2][r] + s[3][r]);
    ps += __shfl_xor(ps, 16);
    ps += __shfl_xor(ps, 32);
    lst += ps;
    // pack P: lane's 16 values are exactly its PV A-fragments (key permutation!)
    unsigned pw[8];
#pragma unroll
    for (int ni = 0; ni < 4; ++ni) {
      unsigned a, c;
      asm("v_cvt_pk_bf16_f32 %0, %1, %2" : "=v"(a) : "v"(s[ni][0]), "v"(s[ni][1]));
      asm("v_cvt_pk_bf16_f32 %0, %1, %2" : "=v"(c) : "v"(s[ni][2]), "v"(s[ni][3]));
      pw[ni * 2] = a; pw[ni * 2 + 1] = c;
    }
    u32x4 apw0 = {pw[0], pw[1], pw[4], pw[5]};   // logical k: lg*8 + 0..7       (ks=0)
    u32x4 apw1 = {pw[2], pw[3], pw[6], pw[7]};   // logical k: 32 + lg*8 + 0..7  (ks=1)
    bf16x8 ap0 = __builtin_bit_cast(bf16x8, apw0);
    bf16x8 ap1 = __builtin_bit_cast(bf16x8, apw1);
    // O += P @ V : C row = q (4lg+r), C col = d (lr)
    __builtin_amdgcn_s_setprio(1);
#pragma unroll
    for (int ni = 0; ni < 4; ++ni) {
      int vr = ni * 16 + lr;
      bf16x8 bv0 = *(const bf16x8*)&Vs[cur][vr * 64 + ((lg ^ (lr & 7)) * 8)];
      bf16x8 bv1 = *(const bf16x8*)&Vs[cur][vr * 64 + (((4 + lg) ^ (lr & 7)) * 8)];
      accO[ni] = __builtin_amdgcn_mfma_f32_16x16x32_bf16(ap0, bv0, accO[ni], 0, 0, 0);
      accO[ni] = __builtin_amdgcn_mfma_f32_16x16x32_bf16(ap1, bv1, accO[ni], 0, 0, 0);
    }
    __builtin_amdgcn_s_setprio(0);
    __syncthreads();   // K/V[cur] reads done + stage(t+1) drained (vmcnt 0 at barrier)
    cur ^= 1;
  }
  float linv = 1.0f / lst;
  float lB[4];
#pragma unroll
  for (int r = 0; r < 4; ++r) lB[r] = __shfl(linv, src0 | r);
#pragma unroll
  for (int ni = 0; ni < 4; ++ni)
#pragma unroll
    for (int r = 0; r < 4; ++r) {
      int qg = qw + lg * 4 + r;
      int col = h * NDK + ni * 16 + lr;
      Ob[(size_t)(b * NL + qg) * ND + col] = f2bf(accO[ni][r] * lB[r]);
    }
}

extern "C" void kernel_launch(void* const* d_in, const int* in_sizes, int n_in,
                              void* d_out, int out_size, void* d_ws, size_t ws_size,
                              hipStream_t stream) {
  const float* query  = (const float*)d_in[0];
  const float* keyval = (const float*)d_in[1];
  const int*   mask   = (const int*)d_in[2];
  const float* Wq     = (const float*)d_in[3];
  const float* Wk     = (const float*)d_in[4];
  const float* Wv     = (const float*)d_in[5];
  const float* Wo     = (const float*)d_in[6];
  const float* rel    = (const float*)d_in[7];

  char* ws = (char*)d_ws;
  unsigned short* q_bf  = (unsigned short*)(ws);              // 4096x768 bf16 (query*0.125)
  unsigned short* kv_bf = (unsigned short*)(ws + 6291456);
  unsigned short* Wq_t  = (unsigned short*)(ws + 12582912);   // [N][K] bf16
  unsigned short* Wk_t  = (unsigned short*)(ws + 13762560);
  unsigned short* Wv_t  = (unsigned short*)(ws + 14942208);
  unsigned short* Wo_t  = (unsigned short*)(ws + 16121856);
  unsigned short* Qb    = (unsigned short*)(ws + 17301504);   // [B,L,H,DK]
  unsigned short* Kb    = (unsigned short*)(ws + 23592960);
  unsigned short* Vt    = (unsigned short*)(ws + 29884416);   // [B,768,L] (== [B,H,DK,L])
  unsigned short* Ob    = (unsigned short*)(ws + 36175872);   // [B,L,H*DK]
  float* bias_tab       = (float*)(ws + 42467328);            // [H][4095]
  float* maskadd        = (float*)(ws + 42663936);            // [B][L] additive mask
  int*   maskall        = (int*)(ws + 42680320);              // [B] all-ones flags

  k_bias<<<dim3(192), dim3(256), 0, stream>>>(rel, bias_tab);
  k_maskadd<<<dim3(NB), dim3(256), 0, stream>>>(mask, maskadd, maskall);
  k_conv<<<dim3(3072), dim3(256), 0, stream>>>(query, q_bf, 786432, 0.125f);
  k_conv<<<dim3(3072), dim3(256), 0, stream>>>(keyval, kv_bf, 786432, 1.0f);
  k_wt<<<dim3(24, 24, 4), dim3(32, 8), 0, stream>>>(Wq, Wk, Wv, Wo, Wq_t, Wk_t, Wv_t, Wo_t);
  k_gemm<<<dim3(64, 12), dim3(256), 0, stream>>>(q_bf,  Wq_t, (void*)Qb, NM, ND, ND, 0);
  k_gemm<<<dim3(64, 12), dim3(256), 0, stream>>>(kv_bf, Wk_t, (void*)Kb, NM, ND, ND, 0);
  k_gemm<<<dim3(64, 12), dim3(256), 0, stream>>>(kv_bf, Wv_t, (void*)Vt, NM, ND, ND, 2);
  k_attn<<<dim3(32, 24), dim3(256), 0, stream>>>(Qb, Kb, Vt, bias_tab, maskadd, maskall, Ob);
  k_gemm<<<dim3(64, 12), dim3(256), 0, stream>>>(Ob, Wo_t, d_out, NM, ND, ND, 1);
}

// Round 6
// 123.027 us; speedup vs baseline: 2.1524x; 1.0558x over previous
//
#include <hip/hip_runtime.h>
#include <stdint.h>

typedef __attribute__((ext_vector_type(8))) short bf16x8;
typedef __attribute__((ext_vector_type(4))) float f32x4;
typedef __attribute__((ext_vector_type(4))) unsigned int u32x4;

#define NB 2
#define NL 2048
#define ND 768
#define NH 12
#define NDK 64
#define NM 4096   // NB*NL
#define LOG2E 1.4426950408889634f

__device__ __forceinline__ unsigned short f2bf(float f) {
  unsigned u = __builtin_bit_cast(unsigned, f);
  u += 0x7FFFu + ((u >> 16) & 1u);          // RNE
  return (unsigned short)(u >> 16);
}

__device__ __forceinline__ float fexp2(float x) {
  float r;
  asm("v_exp_f32 %0, %1" : "=v"(r) : "v"(x));
  return r;
}

__device__ __forceinline__ void gl_lds16(const unsigned short* g, unsigned short* l) {
  __builtin_amdgcn_global_load_lds((const __attribute__((address_space(1))) void*)g,
                                   (__attribute__((address_space(3))) void*)l, 16, 0, 0);
}

// ---- T5 relative-position bias table (pre-scaled by log2e): bias_tab[h][d+2047] ----
__global__ void k_bias(const float* __restrict__ rel_emb, float* __restrict__ bias_tab) {
  int idx = blockIdx.x * 256 + threadIdx.x;
  if (idx >= 4095 * NH) return;
  int h = idx % NH;
  int di = idx / NH;
  int rel = di - 2047;          // rel = k - q
  int n = -rel;
  int ret = 0;
  if (n < 0) { ret = 16; n = -n; }
  int b;
  if (n < 8) {
    b = ret + n;
  } else {
    int v = (n >= 91) ? 7 : (n >= 64) ? 6 : (n >= 46) ? 5 : (n >= 32) ? 4
          : (n >= 23) ? 3 : (n >= 16) ? 2 : (n >= 12) ? 1 : 0;
    b = ret + 8 + v;
  }
  bias_tab[h * 4095 + di] = rel_emb[b * NH + h] * LOG2E;
}

// ---- mask -> additive float array + per-batch all-ones flag ----
__global__ void k_maskadd(const int* __restrict__ mask, float* __restrict__ maskadd,
                          int* __restrict__ maskall) {
  __shared__ int red[256];
  int b = blockIdx.x;
  int t = threadIdx.x;
  int acc = 1;
  for (int i = t; i < NL; i += 256) {
    int m = mask[b * NL + i];
    maskadd[b * NL + i] = m ? 0.0f : -1e30f;
    acc &= (m != 0) ? 1 : 0;
  }
  red[t] = acc;
  __syncthreads();
  for (int s2 = 128; s2 > 0; s2 >>= 1) {
    if (t < s2) red[t] &= red[t + s2];
    __syncthreads();
  }
  if (t == 0) maskall[b] = red[0];
}

// ---- fp32 -> bf16, two buffers in one launch (y selects) ----
__global__ void k_conv(const float* __restrict__ s0, const float* __restrict__ s1,
                       unsigned short* __restrict__ d0, unsigned short* __restrict__ d1,
                       int n4) {
  int i = blockIdx.x * 256 + threadIdx.x;
  if (i >= n4) return;
  const float* src = blockIdx.y ? s1 : s0;
  unsigned short* dst = blockIdx.y ? d1 : d0;
  float4 v = ((const float4*)src)[i];
  ushort4 o;
  o.x = f2bf(v.x);
  o.y = f2bf(v.y);
  o.z = f2bf(v.z);
  o.w = f2bf(v.w);
  ((ushort4*)dst)[i] = o;
}

// ---- W [K][N] fp32 -> Wt [N][K] bf16 (768x768), 4 matrices; Wq gets 0.125*log2e ----
__global__ void k_wt(const float* __restrict__ w0, const float* __restrict__ w1,
                     const float* __restrict__ w2, const float* __restrict__ w3,
                     unsigned short* __restrict__ o0, unsigned short* __restrict__ o1,
                     unsigned short* __restrict__ o2, unsigned short* __restrict__ o3) {
  const float* w = (blockIdx.z == 0) ? w0 : (blockIdx.z == 1) ? w1 : (blockIdx.z == 2) ? w2 : w3;
  unsigned short* o = (blockIdx.z == 0) ? o0 : (blockIdx.z == 1) ? o1 : (blockIdx.z == 2) ? o2 : o3;
  float scale = (blockIdx.z == 0) ? 0.125f * LOG2E : 1.0f;
  __shared__ float t[32][33];
  int bx = blockIdx.x * 32, by = blockIdx.y * 32;
  int tx = threadIdx.x, ty = threadIdx.y;
  for (int r = 0; r < 32; r += 8)
    t[ty + r][tx] = w[(by + ty + r) * ND + bx + tx];
  __syncthreads();
  for (int r = 0; r < 32; r += 8)
    o[(bx + ty + r) * ND + by + tx] = f2bf(t[tx][ty + r] * scale);
}

// ---- bf16 MFMA GEMM: C[M,N] = A[M,K]*Bt[N,K]^T. 64x64 tile, BK=64, dbuf LDS,
// global_load_lds w16, XOR-swizzled. mode 1: fp32 row-major out (only used for Wo now)
__global__ __launch_bounds__(256) void k_gemm(const unsigned short* __restrict__ A,
                                              const unsigned short* __restrict__ Bt,
                                              float* __restrict__ Cout,
                                              int Msz, int Nsz, int Ksz) {
  __shared__ unsigned short As[2][4096];
  __shared__ unsigned short Bs[2][4096];
  int tid = threadIdx.x;
  int wave = tid >> 6, lane = tid & 63;
  int lr = lane & 15, lg = lane >> 4;
  int m0 = blockIdx.x * 64, n0 = blockIdx.y * 64;
  int wm = (wave >> 1) * 32, wn = (wave & 1) * 32;
  int srow = tid >> 3, spc = tid & 7;
  int sg = spc ^ (srow & 7);
  const unsigned short* Ag0 = A  + (size_t)(m0 + srow) * Ksz + sg * 8;
  const unsigned short* Ag1 = A  + (size_t)(m0 + 32 + srow) * Ksz + sg * 8;
  const unsigned short* Bg0 = Bt + (size_t)(n0 + srow) * Ksz + sg * 8;
  const unsigned short* Bg1 = Bt + (size_t)(n0 + 32 + srow) * Ksz + sg * 8;
  f32x4 acc[2][2] = {};
  const int KT = Ksz >> 6;
  gl_lds16(Ag0, &As[0][tid * 8]);
  gl_lds16(Ag1, &As[0][2048 + tid * 8]);
  gl_lds16(Bg0, &Bs[0][tid * 8]);
  gl_lds16(Bg1, &Bs[0][2048 + tid * 8]);
  __syncthreads();
  int cur = 0;
  for (int t = 0; t < KT; ++t) {
    if (t + 1 < KT) {
      int k0 = (t + 1) << 6;
      gl_lds16(Ag0 + k0, &As[cur ^ 1][tid * 8]);
      gl_lds16(Ag1 + k0, &As[cur ^ 1][2048 + tid * 8]);
      gl_lds16(Bg0 + k0, &Bs[cur ^ 1][tid * 8]);
      gl_lds16(Bg1 + k0, &Bs[cur ^ 1][2048 + tid * 8]);
    }
#pragma unroll
    for (int ks = 0; ks < 2; ++ks) {
      bf16x8 af[2], bfr[2];
#pragma unroll
      for (int i = 0; i < 2; ++i) {
        int ar = wm + i * 16 + lr;
        af[i] = *(const bf16x8*)&As[cur][ar * 64 + (((ks * 4 + lg) ^ (ar & 7)) * 8)];
        int br = wn + i * 16 + lr;
        bfr[i] = *(const bf16x8*)&Bs[cur][br * 64 + (((ks * 4 + lg) ^ (br & 7)) * 8)];
      }
#pragma unroll
      for (int mi = 0; mi < 2; ++mi)
#pragma unroll
        for (int ni = 0; ni < 2; ++ni)
          acc[mi][ni] = __builtin_amdgcn_mfma_f32_16x16x32_bf16(af[mi], bfr[ni], acc[mi][ni], 0, 0, 0);
    }
    __syncthreads();
    cur ^= 1;
  }
#pragma unroll
  for (int mi = 0; mi < 2; ++mi)
#pragma unroll
    for (int ni = 0; ni < 2; ++ni)
#pragma unroll
      for (int r = 0; r < 4; ++r) {
        int row = m0 + wm + mi * 16 + lg * 4 + r;
        int col = n0 + wn + ni * 16 + lr;
        Cout[(size_t)row * Nsz + col] = acc[mi][ni][r];
      }
}

// ---- fused QKV GEMM: grid (64, 36); z = y/12 selects {Q,K,V} section.
// Bt = concatenated [Wq_t;Wk_t;Wv_t] (2304 x 768). Outputs: Qb/Kb row-major, Vt transposed.
__global__ __launch_bounds__(256) void k_gemm_qkv(const unsigned short* __restrict__ q_bf,
                                                  const unsigned short* __restrict__ kv_bf,
                                                  const unsigned short* __restrict__ Wt,
                                                  unsigned short* __restrict__ Qb,
                                                  unsigned short* __restrict__ Kb,
                                                  unsigned short* __restrict__ Vt) {
  __shared__ unsigned short As[2][4096];
  __shared__ unsigned short Bs[2][4096];
  int tid = threadIdx.x;
  int wave = tid >> 6, lane = tid & 63;
  int lr = lane & 15, lg = lane >> 4;
  int m0 = blockIdx.x * 64;
  int z = blockIdx.y / 12;                 // 0=Q, 1=K, 2=V
  int nc0 = (blockIdx.y - z * 12) * 64;    // col within the 768-wide section
  const unsigned short* A = (z == 0) ? q_bf : kv_bf;
  const unsigned short* Bt = Wt + (size_t)blockIdx.y * 64 * ND;
  int wm = (wave >> 1) * 32, wn = (wave & 1) * 32;
  int srow = tid >> 3, spc = tid & 7;
  int sg = spc ^ (srow & 7);
  const unsigned short* Ag0 = A  + (size_t)(m0 + srow) * ND + sg * 8;
  const unsigned short* Ag1 = A  + (size_t)(m0 + 32 + srow) * ND + sg * 8;
  const unsigned short* Bg0 = Bt + (size_t)srow * ND + sg * 8;
  const unsigned short* Bg1 = Bt + (size_t)(32 + srow) * ND + sg * 8;
  f32x4 acc[2][2] = {};
  const int KT = ND >> 6;
  gl_lds16(Ag0, &As[0][tid * 8]);
  gl_lds16(Ag1, &As[0][2048 + tid * 8]);
  gl_lds16(Bg0, &Bs[0][tid * 8]);
  gl_lds16(Bg1, &Bs[0][2048 + tid * 8]);
  __syncthreads();
  int cur = 0;
  for (int t = 0; t < KT; ++t) {
    if (t + 1 < KT) {
      int k0 = (t + 1) << 6;
      gl_lds16(Ag0 + k0, &As[cur ^ 1][tid * 8]);
      gl_lds16(Ag1 + k0, &As[cur ^ 1][2048 + tid * 8]);
      gl_lds16(Bg0 + k0, &Bs[cur ^ 1][tid * 8]);
      gl_lds16(Bg1 + k0, &Bs[cur ^ 1][2048 + tid * 8]);
    }
#pragma unroll
    for (int ks = 0; ks < 2; ++ks) {
      bf16x8 af[2], bfr[2];
#pragma unroll
      for (int i = 0; i < 2; ++i) {
        int ar = wm + i * 16 + lr;
        af[i] = *(const bf16x8*)&As[cur][ar * 64 + (((ks * 4 + lg) ^ (ar & 7)) * 8)];
        int br = wn + i * 16 + lr;
        bfr[i] = *(const bf16x8*)&Bs[cur][br * 64 + (((ks * 4 + lg) ^ (br & 7)) * 8)];
      }
#pragma unroll
      for (int mi = 0; mi < 2; ++mi)
#pragma unroll
        for (int ni = 0; ni < 2; ++ni)
          acc[mi][ni] = __builtin_amdgcn_mfma_f32_16x16x32_bf16(af[mi], bfr[ni], acc[mi][ni], 0, 0, 0);
    }
    __syncthreads();
    cur ^= 1;
  }
#pragma unroll
  for (int mi = 0; mi < 2; ++mi)
#pragma unroll
    for (int ni = 0; ni < 2; ++ni)
#pragma unroll
      for (int r = 0; r < 4; ++r) {
        int row = m0 + wm + mi * 16 + lg * 4 + r;
        int col = nc0 + wn + ni * 16 + lr;
        unsigned short v = f2bf(acc[mi][ni][r]);
        if (z == 0) {
          Qb[(size_t)row * ND + col] = v;
        } else if (z == 1) {
          Kb[(size_t)row * ND + col] = v;
        } else {
          int bb = row >> 11, l = row & 2047;       // Vt[(bb*768+col)][l]
          Vt[(((size_t)bb * ND + col) << 11) + l] = v;
        }
      }
}

// ---- fused flash attention, swapped-QK^T (exp2 domain), far-tile constant bias,
// defer-max rescale. One (b,h,64-q-tile) per block, 4 waves. 1 barrier/iter.
__global__ __launch_bounds__(256, 3) void k_attn(const unsigned short* __restrict__ Qb,
                                                 const unsigned short* __restrict__ Kb,
                                                 const unsigned short* __restrict__ Vt,
                                                 const float* __restrict__ bias_tab,
                                                 const float* __restrict__ maskadd,
                                                 const int* __restrict__ maskall,
                                                 unsigned short* __restrict__ Ob) {
  __shared__ unsigned short Ks[2][4096];   // [64 phys keys][64 dk], XOR-swizzled chunks
  __shared__ unsigned short Vs[2][4096];   // [64 dk][64 keys natural], XOR-swizzled
  __shared__ float biasw[384];             // near band: biasw[d+191], d = kg-qg in [-191,191]
  int qt = blockIdx.x, bh = blockIdx.y;
  int b = bh / NH, h = bh % NH;
  int tid = threadIdx.x, wave = tid >> 6, lane = tid & 63;
  int lr = lane & 15, lg = lane >> 4;
  int q0 = qt * 64;
  // near-band fill is q0-independent: biasw[i] = tab[h][i + 1856]  (d = i-191)
  for (int i = tid; i < 383; i += 256) biasw[i] = bias_tab[h * 4095 + 1856 + i];
  float cFlo = bias_tab[h * 4095];          // d = -2047 -> bucket 15 (k << q)
  float cFhi = bias_tab[h * 4095 + 4094];   // d = +2047 -> bucket 31 (k >> q)
  const unsigned short* Kbase = Kb + (size_t)(b * NL) * ND + h * NDK;   // + key*768 + dk
  const unsigned short* Vbase = Vt + (size_t)(b * NH + h) * NDK * NL;   // + dk*2048 + key
  int srow = tid >> 3, spc = tid & 7;
  int sg = spc ^ (srow & 7);
  // key permutation: phys row srow stores logical key l0; +32 phys -> l0+4
  int l0 = (srow >> 4) * 32 + ((srow >> 2) & 3) * 8 + (srow & 3);
  const unsigned short* Kg0 = Kbase + (size_t)l0 * ND + sg * 8;
  const unsigned short* Kg1 = Kbase + (size_t)(l0 + 4) * ND + sg * 8;
  const unsigned short* Vg0 = Vbase + (size_t)srow * NL + sg * 8;
  const unsigned short* Vg1 = Vbase + (size_t)(32 + srow) * NL + sg * 8;
  bf16x8 aq[2];
  int qw = q0 + wave * 16;
#pragma unroll
  for (int ks = 0; ks < 2; ++ks)
    aq[ks] = *(const bf16x8*)&Qb[(size_t)(b * NL + qw + lr) * ND + h * NDK + ks * 32 + lg * 8];
  const float* cbase = maskadd + b * NL;
  int nomask = __builtin_amdgcn_readfirstlane(maskall[b]);
  f32x4 accO[4] = {};
  float mst = -1e30f, lst = 0.f;
  int bconst = lg * 8 - wave * 16 - lr + 191 - q0;   // near idx = kt*64 + subk + bconst
  int src0 = (lane & 48) | ((lane >> 2) & 12);
  gl_lds16(Kg0, &Ks[0][tid * 8]);
  gl_lds16(Kg1, &Ks[0][2048 + tid * 8]);
  gl_lds16(Vg0, &Vs[0][tid * 8]);
  gl_lds16(Vg1, &Vs[0][2048 + tid * 8]);
  __syncthreads();
  int cur = 0;
  const int NT = NL / 64;
  for (int kt = 0; kt < NT; ++kt) {
    float4 cv[2][2];
    if (!nomask) {
#pragma unroll
      for (int hf = 0; hf < 2; ++hf)
#pragma unroll
        for (int qd = 0; qd < 2; ++qd)
          cv[hf][qd] = *(const float4*)&cbase[kt * 64 + hf * 32 + lg * 8 + qd * 4];
    }
    if (kt + 1 < NT) {
      size_t kok = (size_t)(kt + 1) * 64 * ND;
      size_t kov = (size_t)(kt + 1) * 64;
      gl_lds16(Kg0 + kok, &Ks[cur ^ 1][tid * 8]);
      gl_lds16(Kg1 + kok, &Ks[cur ^ 1][2048 + tid * 8]);
      gl_lds16(Vg0 + kov, &Vs[cur ^ 1][tid * 8]);
      gl_lds16(Vg1 + kov, &Vs[cur ^ 1][2048 + tid * 8]);
    }
    // bias C-init: far tiles (27/32) use one splat constant; near band reads LDS
    f32x4 s[4];
    int kt64 = kt * 64;
    if (kt64 + 63 < q0 - 90) {
#pragma unroll
      for (int ni = 0; ni < 4; ++ni)
#pragma unroll
        for (int r = 0; r < 4; ++r) s[ni][r] = cFlo;
    } else if (kt64 > q0 + 153) {
#pragma unroll
      for (int ni = 0; ni < 4; ++ni)
#pragma unroll
        for (int r = 0; r < 4; ++r) s[ni][r] = cFhi;
    } else {
#pragma unroll
      for (int ni = 0; ni < 4; ++ni)
#pragma unroll
        for (int r = 0; r < 4; ++r)
          s[ni][r] = biasw[kt64 + (ni & 1) * 32 + (ni >> 1) * 4 + r + bconst];
    }
    if (!nomask) {
#pragma unroll
      for (int ni = 0; ni < 4; ++ni)
#pragma unroll
        for (int r = 0; r < 4; ++r)
          s[ni][r] += ((const float*)&cv[ni & 1][ni >> 1])[r];
    }
    // S^T = K · Q^T (exp2 domain: Q pre-scaled by 0.125*log2e)
    __builtin_amdgcn_s_setprio(1);
#pragma unroll
    for (int ni = 0; ni < 4; ++ni) {
      int kr = ni * 16 + lr;
      bf16x8 bk0 = *(const bf16x8*)&Ks[cur][kr * 64 + ((lg ^ (lr & 7)) * 8)];
      bf16x8 bk1 = *(const bf16x8*)&Ks[cur][kr * 64 + (((4 + lg) ^ (lr & 7)) * 8)];
      s[ni] = __builtin_amdgcn_mfma_f32_16x16x32_bf16(bk0, aq[0], s[ni], 0, 0, 0);
      s[ni] = __builtin_amdgcn_mfma_f32_16x16x32_bf16(bk1, aq[1], s[ni], 0, 0, 0);
    }
    __builtin_amdgcn_s_setprio(0);
    // row-max (lane owns 16 of 64 keys of q-row lr)
    f32x4 t0, t1;
#pragma unroll
    for (int r = 0; r < 4; ++r) t0[r] = fmaxf(s[0][r], s[1][r]);
#pragma unroll
    for (int r = 0; r < 4; ++r) t1[r] = fmaxf(s[2][r], s[3][r]);
#pragma unroll
    for (int r = 0; r < 4; ++r) t0[r] = fmaxf(t0[r], t1[r]);
    float pmax = fmaxf(fmaxf(t0[0], t0[1]), fmaxf(t0[2], t0[3]));
    pmax = fmaxf(pmax, __shfl_xor(pmax, 16));
    pmax = fmaxf(pmax, __shfl_xor(pmax, 32));
    // defer-max: only rescale when some row grew past mst + 8 (in exp2 domain)
    if (!__all(pmax - mst <= 8.0f)) {
      float mnew = fmaxf(mst, pmax);
      float sc = fexp2(mst - mnew);
      float scB[4];
#pragma unroll
      for (int r = 0; r < 4; ++r) scB[r] = __shfl(sc, src0 | r);
#pragma unroll
      for (int ni = 0; ni < 4; ++ni)
#pragma unroll
        for (int r = 0; r < 4; ++r) accO[ni][r] *= scB[r];
      lst *= sc;
      mst = mnew;
    }
#pragma unroll
    for (int ni = 0; ni < 4; ++ni)
#pragma unroll
      for (int r = 0; r < 4; ++r) s[ni][r] = fexp2(s[ni][r] - mst);
    float ps = 0.f;
#pragma unroll
    for (int r = 0; r < 4; ++r) ps += (s[0][r] + s[1][r]) + (s[2][r] + s[3][r]);
    ps += __shfl_xor(ps, 16);
    ps += __shfl_xor(ps, 32);
    lst += ps;
    // pack P: lane's 16 values are exactly its PV A-fragments (key permutation)
    unsigned pw[8];
#pragma unroll
    for (int ni = 0; ni < 4; ++ni) {
      unsigned a, c;
      asm("v_cvt_pk_bf16_f32 %0, %1, %2" : "=v"(a) : "v"(s[ni][0]), "v"(s[ni][1]));
      asm("v_cvt_pk_bf16_f32 %0, %1, %2" : "=v"(c) : "v"(s[ni][2]), "v"(s[ni][3]));
      pw[ni * 2] = a; pw[ni * 2 + 1] = c;
    }
    u32x4 apw0 = {pw[0], pw[1], pw[4], pw[5]};
    u32x4 apw1 = {pw[2], pw[3], pw[6], pw[7]};
    bf16x8 ap0 = __builtin_bit_cast(bf16x8, apw0);
    bf16x8 ap1 = __builtin_bit_cast(bf16x8, apw1);
    // O += P @ V
    __builtin_amdgcn_s_setprio(1);
#pragma unroll
    for (int ni = 0; ni < 4; ++ni) {
      int vr = ni * 16 + lr;
      bf16x8 bv0 = *(const bf16x8*)&Vs[cur][vr * 64 + ((lg ^ (lr & 7)) * 8)];
      bf16x8 bv1 = *(const bf16x8*)&Vs[cur][vr * 64 + (((4 + lg) ^ (lr & 7)) * 8)];
      accO[ni] = __builtin_amdgcn_mfma_f32_16x16x32_bf16(ap0, bv0, accO[ni], 0, 0, 0);
      accO[ni] = __builtin_amdgcn_mfma_f32_16x16x32_bf16(ap1, bv1, accO[ni], 0, 0, 0);
    }
    __builtin_amdgcn_s_setprio(0);
    __syncthreads();   // K/V[cur] reads done + stage(t+1) drained
    cur ^= 1;
  }
  float linv = 1.0f / lst;
  float lB[4];
#pragma unroll
  for (int r = 0; r < 4; ++r) lB[r] = __shfl(linv, src0 | r);
#pragma unroll
  for (int ni = 0; ni < 4; ++ni)
#pragma unroll
    for (int r = 0; r < 4; ++r) {
      int qg = qw + lg * 4 + r;
      int col = h * NDK + ni * 16 + lr;
      Ob[(size_t)(b * NL + qg) * ND + col] = f2bf(accO[ni][r] * lB[r]);
    }
}

extern "C" void kernel_launch(void* const* d_in, const int* in_sizes, int n_in,
                              void* d_out, int out_size, void* d_ws, size_t ws_size,
                              hipStream_t stream) {
  const float* query  = (const float*)d_in[0];
  const float* keyval = (const float*)d_in[1];
  const int*   mask   = (const int*)d_in[2];
  const float* Wq     = (const float*)d_in[3];
  const float* Wk     = (const float*)d_in[4];
  const float* Wv     = (const float*)d_in[5];
  const float* Wo     = (const float*)d_in[6];
  const float* rel    = (const float*)d_in[7];

  char* ws = (char*)d_ws;
  unsigned short* q_bf  = (unsigned short*)(ws);              // 4096x768 bf16
  unsigned short* kv_bf = (unsigned short*)(ws + 6291456);
  unsigned short* Wq_t  = (unsigned short*)(ws + 12582912);   // [N][K] bf16 (x 0.125*log2e)
  unsigned short* Wk_t  = (unsigned short*)(ws + 13762560);   // contiguous after Wq_t
  unsigned short* Wv_t  = (unsigned short*)(ws + 14942208);
  unsigned short* Wo_t  = (unsigned short*)(ws + 16121856);
  unsigned short* Qb    = (unsigned short*)(ws + 17301504);   // [B,L,H,DK]
  unsigned short* Kb    = (unsigned short*)(ws + 23592960);
  unsigned short* Vt    = (unsigned short*)(ws + 29884416);   // [B,768,L]
  unsigned short* Ob    = (unsigned short*)(ws + 36175872);   // [B,L,H*DK]
  float* bias_tab       = (float*)(ws + 42467328);            // [H][4095], x log2e
  float* maskadd        = (float*)(ws + 42663936);            // [B][L]
  int*   maskall        = (int*)(ws + 42680320);              // [B]

  k_bias<<<dim3(192), dim3(256), 0, stream>>>(rel, bias_tab);
  k_maskadd<<<dim3(NB), dim3(256), 0, stream>>>(mask, maskadd, maskall);
  k_conv<<<dim3(3072, 2), dim3(256), 0, stream>>>(query, keyval, q_bf, kv_bf, 786432);
  k_wt<<<dim3(24, 24, 4), dim3(32, 8), 0, stream>>>(Wq, Wk, Wv, Wo, Wq_t, Wk_t, Wv_t, Wo_t);
  k_gemm_qkv<<<dim3(64, 36), dim3(256), 0, stream>>>(q_bf, kv_bf, Wq_t, Qb, Kb, Vt);
  k_attn<<<dim3(32, 24), dim3(256), 0, stream>>>(Qb, Kb, Vt, bias_tab, maskadd, maskall, Ob);
  k_gemm<<<dim3(64, 12), dim3(256), 0, stream>>>(Ob, Wo_t, (float*)d_out, NM, ND, ND);
}

// Round 7
// 118.032 us; speedup vs baseline: 2.2435x; 1.0423x over previous
//
#include <hip/hip_runtime.h>
#include <stdint.h>

typedef __attribute__((ext_vector_type(8))) short bf16x8;
typedef __attribute__((ext_vector_type(4))) float f32x4;
typedef __attribute__((ext_vector_type(4))) unsigned int u32x4;

#define NB 2
#define NL 2048
#define ND 768
#define NH 12
#define NDK 64
#define NM 4096   // NB*NL
#define LOG2E 1.4426950408889634f

__device__ __forceinline__ unsigned short f2bf(float f) {
  unsigned u = __builtin_bit_cast(unsigned, f);
  u += 0x7FFFu + ((u >> 16) & 1u);          // RNE
  return (unsigned short)(u >> 16);
}

__device__ __forceinline__ float fexp2(float x) {
  float r;
  asm("v_exp_f32 %0, %1" : "=v"(r) : "v"(x));
  return r;
}

__device__ __forceinline__ void gl_lds16(const unsigned short* g, unsigned short* l) {
  __builtin_amdgcn_global_load_lds((const __attribute__((address_space(1))) void*)g,
                                   (__attribute__((address_space(3))) void*)l, 16, 0, 0);
}

// ---- merged prep: conv (0..6143) | wt (6144..8447) | bias (8448..8639) | maskadd (8640..8641)
__global__ __launch_bounds__(256) void k_prep(const float* __restrict__ query,
                                              const float* __restrict__ keyval,
                                              const float* __restrict__ Wq,
                                              const float* __restrict__ Wk,
                                              const float* __restrict__ Wv,
                                              const float* __restrict__ Wo,
                                              const float* __restrict__ rel_emb,
                                              const int* __restrict__ mask,
                                              unsigned short* __restrict__ q_bf,
                                              unsigned short* __restrict__ kv_bf,
                                              unsigned short* __restrict__ Wq_t,
                                              unsigned short* __restrict__ Wk_t,
                                              unsigned short* __restrict__ Wv_t,
                                              unsigned short* __restrict__ Wo_t,
                                              float* __restrict__ bias_tab,
                                              float* __restrict__ maskadd,
                                              int* __restrict__ maskall) {
  __shared__ float shbuf[32 * 33];
  int blk = blockIdx.x, tid = threadIdx.x;
  if (blk < 6144) {
    // fp32 -> bf16 (query scaled later via Wq; here plain convert)
    int y = blk / 3072;
    int i = (blk - y * 3072) * 256 + tid;
    const float* src = y ? keyval : query;
    unsigned short* dst = y ? kv_bf : q_bf;
    float4 v = ((const float4*)src)[i];
    ushort4 o;
    o.x = f2bf(v.x); o.y = f2bf(v.y); o.z = f2bf(v.z); o.w = f2bf(v.w);
    ((ushort4*)dst)[i] = o;
  } else if (blk < 8448) {
    // W [K][N] -> Wt [N][K] bf16; Wq gets 0.125*log2e
    int rel = blk - 6144;
    int z = rel / 576, r2 = rel - z * 576;
    int bx = (r2 % 24) * 32, by = (r2 / 24) * 32;
    const float* w = (z == 0) ? Wq : (z == 1) ? Wk : (z == 2) ? Wv : Wo;
    unsigned short* o = (z == 0) ? Wq_t : (z == 1) ? Wk_t : (z == 2) ? Wv_t : Wo_t;
    float scale = (z == 0) ? 0.125f * LOG2E : 1.0f;
    int tx = tid & 31, ty = tid >> 5;
    float (*t)[33] = (float(*)[33])shbuf;
    for (int r = 0; r < 32; r += 8)
      t[ty + r][tx] = w[(by + ty + r) * ND + bx + tx];
    __syncthreads();
    for (int r = 0; r < 32; r += 8)
      o[(bx + ty + r) * ND + by + tx] = f2bf(t[tx][ty + r] * scale);
  } else if (blk < 8640) {
    // T5 bias table (pre-scaled by log2e); exact integer bucket thresholds
    int idx = (blk - 8448) * 256 + tid;
    if (idx >= 4095 * NH) return;
    int h = idx % NH;
    int di = idx / NH;
    int rel = di - 2047;          // rel = k - q
    int n = -rel;
    int ret = 0;
    if (n < 0) { ret = 16; n = -n; }
    int b;
    if (n < 8) {
      b = ret + n;
    } else {
      int v = (n >= 91) ? 7 : (n >= 64) ? 6 : (n >= 46) ? 5 : (n >= 32) ? 4
            : (n >= 23) ? 3 : (n >= 16) ? 2 : (n >= 12) ? 1 : 0;
      b = ret + 8 + v;
    }
    bias_tab[h * 4095 + di] = rel_emb[b * NH + h] * LOG2E;
  } else {
    // mask -> additive + all-ones flag
    int b = blk - 8640;
    int* red = (int*)shbuf;
    int acc = 1;
    for (int i = tid; i < NL; i += 256) {
      int m = mask[b * NL + i];
      maskadd[b * NL + i] = m ? 0.0f : -1e30f;
      acc &= (m != 0) ? 1 : 0;
    }
    red[tid] = acc;
    __syncthreads();
    for (int s2 = 128; s2 > 0; s2 >>= 1) {
      if (tid < s2) red[tid] &= red[tid + s2];
      __syncthreads();
    }
    if (tid == 0) maskall[b] = red[0];
  }
}

// ---- fused QKV GEMM, 128x128 tile (m97 structure): grid (32, 18); y/6 = {Q,K,V}.
// Bt = concatenated [Wq_t;Wk_t;Wv_t] (2304 x 768). BK=64, 2-barrier loop, gl_lds w16.
__global__ __launch_bounds__(256) void k_gemm_qkv(const unsigned short* __restrict__ q_bf,
                                                  const unsigned short* __restrict__ kv_bf,
                                                  const unsigned short* __restrict__ Wt,
                                                  unsigned short* __restrict__ Qb,
                                                  unsigned short* __restrict__ Kb,
                                                  unsigned short* __restrict__ Vt) {
  __shared__ unsigned short As[8192];   // [128 rows][64 k], 16 KB
  __shared__ unsigned short Bs[8192];
  int tid = threadIdx.x;
  int wave = tid >> 6, lane = tid & 63;
  int lr = lane & 15, lg = lane >> 4;
  int m0 = blockIdx.x * 128;
  int z = blockIdx.y / 6;                  // 0=Q, 1=K, 2=V
  int nc0 = (blockIdx.y % 6) * 128;        // col within the 768-wide section
  const unsigned short* A  = (z == 0) ? q_bf : kv_bf;
  const unsigned short* Bt = Wt + (size_t)blockIdx.y * 128 * ND;
  int wm = (wave >> 1) * 64, wn = (wave & 1) * 64;
  int srow = tid >> 3, spc = tid & 7;
  int sg = spc ^ (srow & 7);               // inverse swizzle on global source
  const unsigned short* Ag = A  + (size_t)(m0 + srow) * ND + sg * 8;
  const unsigned short* Bg = Bt + (size_t)srow * ND + sg * 8;
  f32x4 acc[4][4] = {};
  for (int t = 0; t < ND / 64; ++t) {
    int k0 = t * 64;
#pragma unroll
    for (int s = 0; s < 4; ++s) {
      gl_lds16(Ag + (size_t)(s * 32) * ND + k0, &As[s * 2048 + tid * 8]);
      gl_lds16(Bg + (size_t)(s * 32) * ND + k0, &Bs[s * 2048 + tid * 8]);
    }
    __syncthreads();                       // stage drained (vmcnt 0 at barrier)
#pragma unroll
    for (int ks = 0; ks < 2; ++ks) {
      bf16x8 af[4], bfr[4];
#pragma unroll
      for (int i = 0; i < 4; ++i) {
        int ar = wm + i * 16 + lr;
        af[i] = *(const bf16x8*)&As[ar * 64 + (((ks * 4 + lg) ^ (ar & 7)) * 8)];
        int br = wn + i * 16 + lr;
        bfr[i] = *(const bf16x8*)&Bs[br * 64 + (((ks * 4 + lg) ^ (br & 7)) * 8)];
      }
#pragma unroll
      for (int mi = 0; mi < 4; ++mi)
#pragma unroll
        for (int ni = 0; ni < 4; ++ni)
          acc[mi][ni] = __builtin_amdgcn_mfma_f32_16x16x32_bf16(af[mi], bfr[ni], acc[mi][ni], 0, 0, 0);
    }
    __syncthreads();                       // reads done before next stage overwrites
  }
#pragma unroll
  for (int mi = 0; mi < 4; ++mi)
#pragma unroll
    for (int ni = 0; ni < 4; ++ni)
#pragma unroll
      for (int r = 0; r < 4; ++r) {
        int row = m0 + wm + mi * 16 + lg * 4 + r;   // C/D: col=lane&15, row=(lane>>4)*4+reg
        int col = nc0 + wn + ni * 16 + lr;
        unsigned short v = f2bf(acc[mi][ni][r]);
        if (z == 0) {
          Qb[(size_t)row * ND + col] = v;
        } else if (z == 1) {
          Kb[(size_t)row * ND + col] = v;
        } else {
          int bb = row >> 11, l = row & 2047;       // Vt[(bb*768+col)][l]
          Vt[(((size_t)bb * ND + col) << 11) + l] = v;
        }
      }
}

// ---- out-proj GEMM: C[M,N] fp32 = A[M,K] bf16 * Bt[N,K]^T. 128x64 tile, BK=64.
__global__ __launch_bounds__(256) void k_gemm(const unsigned short* __restrict__ A,
                                              const unsigned short* __restrict__ Bt,
                                              float* __restrict__ Cout,
                                              int Msz, int Nsz, int Ksz) {
  __shared__ unsigned short As[8192];   // [128][64]
  __shared__ unsigned short Bs[4096];   // [64][64]
  int tid = threadIdx.x;
  int wave = tid >> 6, lane = tid & 63;
  int lr = lane & 15, lg = lane >> 4;
  int m0 = blockIdx.x * 128, n0 = blockIdx.y * 64;
  int wm = (wave >> 1) * 64, wn = (wave & 1) * 32;
  int srow = tid >> 3, spc = tid & 7;
  int sg = spc ^ (srow & 7);
  const unsigned short* Ag = A  + (size_t)(m0 + srow) * Ksz + sg * 8;
  const unsigned short* Bg = Bt + (size_t)(n0 + srow) * Ksz + sg * 8;
  f32x4 acc[4][2] = {};
  for (int t = 0; t < Ksz / 64; ++t) {
    int k0 = t * 64;
#pragma unroll
    for (int s = 0; s < 4; ++s)
      gl_lds16(Ag + (size_t)(s * 32) * Ksz + k0, &As[s * 2048 + tid * 8]);
#pragma unroll
    for (int s = 0; s < 2; ++s)
      gl_lds16(Bg + (size_t)(s * 32) * Ksz + k0, &Bs[s * 2048 + tid * 8]);
    __syncthreads();
#pragma unroll
    for (int ks = 0; ks < 2; ++ks) {
      bf16x8 af[4], bfr[2];
#pragma unroll
      for (int i = 0; i < 4; ++i) {
        int ar = wm + i * 16 + lr;
        af[i] = *(const bf16x8*)&As[ar * 64 + (((ks * 4 + lg) ^ (ar & 7)) * 8)];
      }
#pragma unroll
      for (int i = 0; i < 2; ++i) {
        int br = wn + i * 16 + lr;
        bfr[i] = *(const bf16x8*)&Bs[br * 64 + (((ks * 4 + lg) ^ (br & 7)) * 8)];
      }
#pragma unroll
      for (int mi = 0; mi < 4; ++mi)
#pragma unroll
        for (int ni = 0; ni < 2; ++ni)
          acc[mi][ni] = __builtin_amdgcn_mfma_f32_16x16x32_bf16(af[mi], bfr[ni], acc[mi][ni], 0, 0, 0);
    }
    __syncthreads();
  }
#pragma unroll
  for (int mi = 0; mi < 4; ++mi)
#pragma unroll
    for (int ni = 0; ni < 2; ++ni)
#pragma unroll
      for (int r = 0; r < 4; ++r) {
        int row = m0 + wm + mi * 16 + lg * 4 + r;
        int col = n0 + wn + ni * 16 + lr;
        Cout[(size_t)row * Nsz + col] = acc[mi][ni][r];
      }
}

// ---- fused flash attention, swapped-QK^T (exp2 domain), far-tile constant bias,
// defer-max rescale. One (b,h,64-q-tile) per block, 4 waves. 1 barrier/iter.
__global__ __launch_bounds__(256, 3) void k_attn(const unsigned short* __restrict__ Qb,
                                                 const unsigned short* __restrict__ Kb,
                                                 const unsigned short* __restrict__ Vt,
                                                 const float* __restrict__ bias_tab,
                                                 const float* __restrict__ maskadd,
                                                 const int* __restrict__ maskall,
                                                 unsigned short* __restrict__ Ob) {
  __shared__ unsigned short Ks[2][4096];   // [64 phys keys][64 dk], XOR-swizzled chunks
  __shared__ unsigned short Vs[2][4096];   // [64 dk][64 keys natural], XOR-swizzled
  __shared__ float biasw[384];             // near band: biasw[d+191], d = kg-qg in [-191,191]
  int qt = blockIdx.x, bh = blockIdx.y;
  int b = bh / NH, h = bh % NH;
  int tid = threadIdx.x, wave = tid >> 6, lane = tid & 63;
  int lr = lane & 15, lg = lane >> 4;
  int q0 = qt * 64;
  for (int i = tid; i < 383; i += 256) biasw[i] = bias_tab[h * 4095 + 1856 + i];
  float cFlo = bias_tab[h * 4095];          // d = -2047 -> bucket 15 (k << q)
  float cFhi = bias_tab[h * 4095 + 4094];   // d = +2047 -> bucket 31 (k >> q)
  const unsigned short* Kbase = Kb + (size_t)(b * NL) * ND + h * NDK;   // + key*768 + dk
  const unsigned short* Vbase = Vt + (size_t)(b * NH + h) * NDK * NL;   // + dk*2048 + key
  int srow = tid >> 3, spc = tid & 7;
  int sg = spc ^ (srow & 7);
  // key permutation: phys row srow stores logical key l0; +32 phys -> l0+4
  int l0 = (srow >> 4) * 32 + ((srow >> 2) & 3) * 8 + (srow & 3);
  const unsigned short* Kg0 = Kbase + (size_t)l0 * ND + sg * 8;
  const unsigned short* Kg1 = Kbase + (size_t)(l0 + 4) * ND + sg * 8;
  const unsigned short* Vg0 = Vbase + (size_t)srow * NL + sg * 8;
  const unsigned short* Vg1 = Vbase + (size_t)(32 + srow) * NL + sg * 8;
  bf16x8 aq[2];
  int qw = q0 + wave * 16;
#pragma unroll
  for (int ks = 0; ks < 2; ++ks)
    aq[ks] = *(const bf16x8*)&Qb[(size_t)(b * NL + qw + lr) * ND + h * NDK + ks * 32 + lg * 8];
  const float* cbase = maskadd + b * NL;
  int nomask = __builtin_amdgcn_readfirstlane(maskall[b]);
  f32x4 accO[4] = {};
  float mst = -1e30f, lst = 0.f;
  int bconst = lg * 8 - wave * 16 - lr + 191 - q0;   // near idx = kt*64 + subk + bconst
  int src0 = (lane & 48) | ((lane >> 2) & 12);
  gl_lds16(Kg0, &Ks[0][tid * 8]);
  gl_lds16(Kg1, &Ks[0][2048 + tid * 8]);
  gl_lds16(Vg0, &Vs[0][tid * 8]);
  gl_lds16(Vg1, &Vs[0][2048 + tid * 8]);
  __syncthreads();
  int cur = 0;
  const int NT = NL / 64;
  for (int kt = 0; kt < NT; ++kt) {
    float4 cv[2][2];
    if (!nomask) {
#pragma unroll
      for (int hf = 0; hf < 2; ++hf)
#pragma unroll
        for (int qd = 0; qd < 2; ++qd)
          cv[hf][qd] = *(const float4*)&cbase[kt * 64 + hf * 32 + lg * 8 + qd * 4];
    }
    if (kt + 1 < NT) {
      size_t kok = (size_t)(kt + 1) * 64 * ND;
      size_t kov = (size_t)(kt + 1) * 64;
      gl_lds16(Kg0 + kok, &Ks[cur ^ 1][tid * 8]);
      gl_lds16(Kg1 + kok, &Ks[cur ^ 1][2048 + tid * 8]);
      gl_lds16(Vg0 + kov, &Vs[cur ^ 1][tid * 8]);
      gl_lds16(Vg1 + kov, &Vs[cur ^ 1][2048 + tid * 8]);
    }
    // bias C-init: far tiles (27/32) use one splat constant; near band reads LDS
    f32x4 s[4];
    int kt64 = kt * 64;
    if (kt64 + 63 < q0 - 90) {
#pragma unroll
      for (int ni = 0; ni < 4; ++ni)
#pragma unroll
        for (int r = 0; r < 4; ++r) s[ni][r] = cFlo;
    } else if (kt64 > q0 + 153) {
#pragma unroll
      for (int ni = 0; ni < 4; ++ni)
#pragma unroll
        for (int r = 0; r < 4; ++r) s[ni][r] = cFhi;
    } else {
#pragma unroll
      for (int ni = 0; ni < 4; ++ni)
#pragma unroll
        for (int r = 0; r < 4; ++r)
          s[ni][r] = biasw[kt64 + (ni & 1) * 32 + (ni >> 1) * 4 + r + bconst];
    }
    if (!nomask) {
#pragma unroll
      for (int ni = 0; ni < 4; ++ni)
#pragma unroll
        for (int r = 0; r < 4; ++r)
          s[ni][r] += ((const float*)&cv[ni & 1][ni >> 1])[r];
    }
    // S^T = K · Q^T (exp2 domain: Q pre-scaled by 0.125*log2e)
    __builtin_amdgcn_s_setprio(1);
#pragma unroll
    for (int ni = 0; ni < 4; ++ni) {
      int kr = ni * 16 + lr;
      bf16x8 bk0 = *(const bf16x8*)&Ks[cur][kr * 64 + ((lg ^ (lr & 7)) * 8)];
      bf16x8 bk1 = *(const bf16x8*)&Ks[cur][kr * 64 + (((4 + lg) ^ (lr & 7)) * 8)];
      s[ni] = __builtin_amdgcn_mfma_f32_16x16x32_bf16(bk0, aq[0], s[ni], 0, 0, 0);
      s[ni] = __builtin_amdgcn_mfma_f32_16x16x32_bf16(bk1, aq[1], s[ni], 0, 0, 0);
    }
    __builtin_amdgcn_s_setprio(0);
    // row-max (lane owns 16 of 64 keys of q-row lr)
    f32x4 t0, t1;
#pragma unroll
    for (int r = 0; r < 4; ++r) t0[r] = fmaxf(s[0][r], s[1][r]);
#pragma unroll
    for (int r = 0; r < 4; ++r) t1[r] = fmaxf(s[2][r], s[3][r]);
#pragma unroll
    for (int r = 0; r < 4; ++r) t0[r] = fmaxf(t0[r], t1[r]);
    float pmax = fmaxf(fmaxf(t0[0], t0[1]), fmaxf(t0[2], t0[3]));
    pmax = fmaxf(pmax, __shfl_xor(pmax, 16));
    pmax = fmaxf(pmax, __shfl_xor(pmax, 32));
    // defer-max: only rescale when some row grew past mst + 8 (in exp2 domain)
    if (!__all(pmax - mst <= 8.0f)) {
      float mnew = fmaxf(mst, pmax);
      float sc = fexp2(mst - mnew);
      float scB[4];
#pragma unroll
      for (int r = 0; r < 4; ++r) scB[r] = __shfl(sc, src0 | r);
#pragma unroll
      for (int ni = 0; ni < 4; ++ni)
#pragma unroll
        for (int r = 0; r < 4; ++r) accO[ni][r] *= scB[r];
      lst *= sc;
      mst = mnew;
    }
#pragma unroll
    for (int ni = 0; ni < 4; ++ni)
#pragma unroll
      for (int r = 0; r < 4; ++r) s[ni][r] = fexp2(s[ni][r] - mst);
    float ps = 0.f;
#pragma unroll
    for (int r = 0; r < 4; ++r) ps += (s[0][r] + s[1][r]) + (s[2][r] + s[3][r]);
    ps += __shfl_xor(ps, 16);
    ps += __shfl_xor(ps, 32);
    lst += ps;
    // pack P: lane's 16 values are exactly its PV A-fragments (key permutation)
    unsigned pw[8];
#pragma unroll
    for (int ni = 0; ni < 4; ++ni) {
      unsigned a, c;
      asm("v_cvt_pk_bf16_f32 %0, %1, %2" : "=v"(a) : "v"(s[ni][0]), "v"(s[ni][1]));
      asm("v_cvt_pk_bf16_f32 %0, %1, %2" : "=v"(c) : "v"(s[ni][2]), "v"(s[ni][3]));
      pw[ni * 2] = a; pw[ni * 2 + 1] = c;
    }
    u32x4 apw0 = {pw[0], pw[1], pw[4], pw[5]};
    u32x4 apw1 = {pw[2], pw[3], pw[6], pw[7]};
    bf16x8 ap0 = __builtin_bit_cast(bf16x8, apw0);
    bf16x8 ap1 = __builtin_bit_cast(bf16x8, apw1);
    // O += P @ V
    __builtin_amdgcn_s_setprio(1);
#pragma unroll
    for (int ni = 0; ni < 4; ++ni) {
      int vr = ni * 16 + lr;
      bf16x8 bv0 = *(const bf16x8*)&Vs[cur][vr * 64 + ((lg ^ (lr & 7)) * 8)];
      bf16x8 bv1 = *(const bf16x8*)&Vs[cur][vr * 64 + (((4 + lg) ^ (lr & 7)) * 8)];
      accO[ni] = __builtin_amdgcn_mfma_f32_16x16x32_bf16(ap0, bv0, accO[ni], 0, 0, 0);
      accO[ni] = __builtin_amdgcn_mfma_f32_16x16x32_bf16(ap1, bv1, accO[ni], 0, 0, 0);
    }
    __builtin_amdgcn_s_setprio(0);
    __syncthreads();   // K/V[cur] reads done + stage(t+1) drained
    cur ^= 1;
  }
  float linv = 1.0f / lst;
  float lB[4];
#pragma unroll
  for (int r = 0; r < 4; ++r) lB[r] = __shfl(linv, src0 | r);
#pragma unroll
  for (int ni = 0; ni < 4; ++ni)
#pragma unroll
    for (int r = 0; r < 4; ++r) {
      int qg = qw + lg * 4 + r;
      int col = h * NDK + ni * 16 + lr;
      Ob[(size_t)(b * NL + qg) * ND + col] = f2bf(accO[ni][r] * lB[r]);
    }
}

extern "C" void kernel_launch(void* const* d_in, const int* in_sizes, int n_in,
                              void* d_out, int out_size, void* d_ws, size_t ws_size,
                              hipStream_t stream) {
  const float* query  = (const float*)d_in[0];
  const float* keyval = (const float*)d_in[1];
  const int*   mask   = (const int*)d_in[2];
  const float* Wq     = (const float*)d_in[3];
  const float* Wk     = (const float*)d_in[4];
  const float* Wv     = (const float*)d_in[5];
  const float* Wo     = (const float*)d_in[6];
  const float* rel    = (const float*)d_in[7];

  char* ws = (char*)d_ws;
  unsigned short* q_bf  = (unsigned short*)(ws);              // 4096x768 bf16
  unsigned short* kv_bf = (unsigned short*)(ws + 6291456);
  unsigned short* Wq_t  = (unsigned short*)(ws + 12582912);   // [N][K] bf16 (x 0.125*log2e)
  unsigned short* Wk_t  = (unsigned short*)(ws + 13762560);   // contiguous after Wq_t
  unsigned short* Wv_t  = (unsigned short*)(ws + 14942208);
  unsigned short* Wo_t  = (unsigned short*)(ws + 16121856);
  unsigned short* Qb    = (unsigned short*)(ws + 17301504);   // [B,L,H,DK]
  unsigned short* Kb    = (unsigned short*)(ws + 23592960);
  unsigned short* Vt    = (unsigned short*)(ws + 29884416);   // [B,768,L]
  unsigned short* Ob    = (unsigned short*)(ws + 36175872);   // [B,L,H*DK]
  float* bias_tab       = (float*)(ws + 42467328);            // [H][4095], x log2e
  float* maskadd        = (float*)(ws + 42663936);            // [B][L]
  int*   maskall        = (int*)(ws + 42680320);              // [B]

  k_prep<<<dim3(8642), dim3(256), 0, stream>>>(query, keyval, Wq, Wk, Wv, Wo, rel, mask,
                                               q_bf, kv_bf, Wq_t, Wk_t, Wv_t, Wo_t,
                                               bias_tab, maskadd, maskall);
  k_gemm_qkv<<<dim3(32, 18), dim3(256), 0, stream>>>(q_bf, kv_bf, Wq_t, Qb, Kb, Vt);
  k_attn<<<dim3(32, 24), dim3(256), 0, stream>>>(Qb, Kb, Vt, bias_tab, maskadd, maskall, Ob);
  k_gemm<<<dim3(32, 12), dim3(256), 0, stream>>>(Ob, Wo_t, (float*)d_out, NM, ND, ND);
}

// Round 8
// 117.905 us; speedup vs baseline: 2.2459x; 1.0011x over previous
//
#include <hip/hip_runtime.h>
#include <stdint.h>

typedef __attribute__((ext_vector_type(8))) short bf16x8;
typedef __attribute__((ext_vector_type(4))) float f32x4;
typedef __attribute__((ext_vector_type(4))) unsigned int u32x4;

#define NB 2
#define NL 2048
#define ND 768
#define NH 12
#define NDK 64
#define NM 4096   // NB*NL
#define LOG2E 1.4426950408889634f

__device__ __forceinline__ unsigned short f2bf(float f) {
  unsigned u = __builtin_bit_cast(unsigned, f);
  u += 0x7FFFu + ((u >> 16) & 1u);          // RNE
  return (unsigned short)(u >> 16);
}

__device__ __forceinline__ float fexp2(float x) {
  float r;
  asm("v_exp_f32 %0, %1" : "=v"(r) : "v"(x));
  return r;
}

__device__ __forceinline__ void gl_lds16(const unsigned short* g, unsigned short* l) {
  __builtin_amdgcn_global_load_lds((const __attribute__((address_space(1))) void*)g,
                                   (__attribute__((address_space(3))) void*)l, 16, 0, 0);
}

// ---- merged prep: conv (0..6143) | wt (6144..8447) | bias (8448..8639) | maskadd (8640..8641)
__global__ __launch_bounds__(256) void k_prep(const float* __restrict__ query,
                                              const float* __restrict__ keyval,
                                              const float* __restrict__ Wq,
                                              const float* __restrict__ Wk,
                                              const float* __restrict__ Wv,
                                              const float* __restrict__ Wo,
                                              const float* __restrict__ rel_emb,
                                              const int* __restrict__ mask,
                                              unsigned short* __restrict__ q_bf,
                                              unsigned short* __restrict__ kv_bf,
                                              unsigned short* __restrict__ Wq_t,
                                              unsigned short* __restrict__ Wk_t,
                                              unsigned short* __restrict__ Wv_t,
                                              unsigned short* __restrict__ Wo_t,
                                              float* __restrict__ bias_tab,
                                              float* __restrict__ maskadd,
                                              int* __restrict__ maskall) {
  __shared__ float shbuf[32 * 33];
  int blk = blockIdx.x, tid = threadIdx.x;
  if (blk < 6144) {
    int y = blk / 3072;
    int i = (blk - y * 3072) * 256 + tid;
    const float* src = y ? keyval : query;
    unsigned short* dst = y ? kv_bf : q_bf;
    float4 v = ((const float4*)src)[i];
    ushort4 o;
    o.x = f2bf(v.x); o.y = f2bf(v.y); o.z = f2bf(v.z); o.w = f2bf(v.w);
    ((ushort4*)dst)[i] = o;
  } else if (blk < 8448) {
    int rel = blk - 6144;
    int z = rel / 576, r2 = rel - z * 576;
    int bx = (r2 % 24) * 32, by = (r2 / 24) * 32;
    const float* w = (z == 0) ? Wq : (z == 1) ? Wk : (z == 2) ? Wv : Wo;
    unsigned short* o = (z == 0) ? Wq_t : (z == 1) ? Wk_t : (z == 2) ? Wv_t : Wo_t;
    float scale = (z == 0) ? 0.125f * LOG2E : 1.0f;
    int tx = tid & 31, ty = tid >> 5;
    float (*t)[33] = (float(*)[33])shbuf;
    for (int r = 0; r < 32; r += 8)
      t[ty + r][tx] = w[(by + ty + r) * ND + bx + tx];
    __syncthreads();
    for (int r = 0; r < 32; r += 8)
      o[(bx + ty + r) * ND + by + tx] = f2bf(t[tx][ty + r] * scale);
  } else if (blk < 8640) {
    int idx = (blk - 8448) * 256 + tid;
    if (idx >= 4095 * NH) return;
    int h = idx % NH;
    int di = idx / NH;
    int rel = di - 2047;          // rel = k - q
    int n = -rel;
    int ret = 0;
    if (n < 0) { ret = 16; n = -n; }
    int b;
    if (n < 8) {
      b = ret + n;
    } else {
      int v = (n >= 91) ? 7 : (n >= 64) ? 6 : (n >= 46) ? 5 : (n >= 32) ? 4
            : (n >= 23) ? 3 : (n >= 16) ? 2 : (n >= 12) ? 1 : 0;
      b = ret + 8 + v;
    }
    bias_tab[h * 4095 + di] = rel_emb[b * NH + h] * LOG2E;
  } else {
    int b = blk - 8640;
    int* red = (int*)shbuf;
    int acc = 1;
    for (int i = tid; i < NL; i += 256) {
      int m = mask[b * NL + i];
      maskadd[b * NL + i] = m ? 0.0f : -1e30f;
      acc &= (m != 0) ? 1 : 0;
    }
    red[tid] = acc;
    __syncthreads();
    for (int s2 = 128; s2 > 0; s2 >>= 1) {
      if (tid < s2) red[tid] &= red[tid + s2];
      __syncthreads();
    }
    if (tid == 0) maskall[b] = red[0];
  }
}

// ---- fused QKV GEMM, 128x128 tile: grid (32, 18); y/6 = {Q,K,V}. BK=64, gl_lds w16.
__global__ __launch_bounds__(256) void k_gemm_qkv(const unsigned short* __restrict__ q_bf,
                                                  const unsigned short* __restrict__ kv_bf,
                                                  const unsigned short* __restrict__ Wt,
                                                  unsigned short* __restrict__ Qb,
                                                  unsigned short* __restrict__ Kb,
                                                  unsigned short* __restrict__ Vt) {
  __shared__ unsigned short As[8192];   // [128 rows][64 k], 16 KB
  __shared__ unsigned short Bs[8192];
  int tid = threadIdx.x;
  int wave = tid >> 6, lane = tid & 63;
  int lr = lane & 15, lg = lane >> 4;
  int m0 = blockIdx.x * 128;
  int z = blockIdx.y / 6;                  // 0=Q, 1=K, 2=V
  int nc0 = (blockIdx.y % 6) * 128;
  const unsigned short* A  = (z == 0) ? q_bf : kv_bf;
  const unsigned short* Bt = Wt + (size_t)blockIdx.y * 128 * ND;
  int wm = (wave >> 1) * 64, wn = (wave & 1) * 64;
  int srow = tid >> 3, spc = tid & 7;
  int sg = spc ^ (srow & 7);
  const unsigned short* Ag = A  + (size_t)(m0 + srow) * ND + sg * 8;
  const unsigned short* Bg = Bt + (size_t)srow * ND + sg * 8;
  f32x4 acc[4][4] = {};
  for (int t = 0; t < ND / 64; ++t) {
    int k0 = t * 64;
#pragma unroll
    for (int s = 0; s < 4; ++s) {
      gl_lds16(Ag + (size_t)(s * 32) * ND + k0, &As[s * 2048 + tid * 8]);
      gl_lds16(Bg + (size_t)(s * 32) * ND + k0, &Bs[s * 2048 + tid * 8]);
    }
    __syncthreads();
#pragma unroll
    for (int ks = 0; ks < 2; ++ks) {
      bf16x8 af[4], bfr[4];
#pragma unroll
      for (int i = 0; i < 4; ++i) {
        int ar = wm + i * 16 + lr;
        af[i] = *(const bf16x8*)&As[ar * 64 + (((ks * 4 + lg) ^ (ar & 7)) * 8)];
        int br = wn + i * 16 + lr;
        bfr[i] = *(const bf16x8*)&Bs[br * 64 + (((ks * 4 + lg) ^ (br & 7)) * 8)];
      }
#pragma unroll
      for (int mi = 0; mi < 4; ++mi)
#pragma unroll
        for (int ni = 0; ni < 4; ++ni)
          acc[mi][ni] = __builtin_amdgcn_mfma_f32_16x16x32_bf16(af[mi], bfr[ni], acc[mi][ni], 0, 0, 0);
    }
    __syncthreads();
  }
#pragma unroll
  for (int mi = 0; mi < 4; ++mi)
#pragma unroll
    for (int ni = 0; ni < 4; ++ni)
#pragma unroll
      for (int r = 0; r < 4; ++r) {
        int row = m0 + wm + mi * 16 + lg * 4 + r;
        int col = nc0 + wn + ni * 16 + lr;
        unsigned short v = f2bf(acc[mi][ni][r]);
        if (z == 0) {
          Qb[(size_t)row * ND + col] = v;
        } else if (z == 1) {
          Kb[(size_t)row * ND + col] = v;
        } else {
          int bb = row >> 11, l = row & 2047;
          Vt[(((size_t)bb * ND + col) << 11) + l] = v;
        }
      }
}

// ---- out-proj GEMM: C[M,N] fp32 = A[M,K] bf16 * Bt[N,K]^T. 128x64 tile, BK=64.
__global__ __launch_bounds__(256) void k_gemm(const unsigned short* __restrict__ A,
                                              const unsigned short* __restrict__ Bt,
                                              float* __restrict__ Cout,
                                              int Msz, int Nsz, int Ksz) {
  __shared__ unsigned short As[8192];
  __shared__ unsigned short Bs[4096];
  int tid = threadIdx.x;
  int wave = tid >> 6, lane = tid & 63;
  int lr = lane & 15, lg = lane >> 4;
  int m0 = blockIdx.x * 128, n0 = blockIdx.y * 64;
  int wm = (wave >> 1) * 64, wn = (wave & 1) * 32;
  int srow = tid >> 3, spc = tid & 7;
  int sg = spc ^ (srow & 7);
  const unsigned short* Ag = A  + (size_t)(m0 + srow) * Ksz + sg * 8;
  const unsigned short* Bg = Bt + (size_t)(n0 + srow) * Ksz + sg * 8;
  f32x4 acc[4][2] = {};
  for (int t = 0; t < Ksz / 64; ++t) {
    int k0 = t * 64;
#pragma unroll
    for (int s = 0; s < 4; ++s)
      gl_lds16(Ag + (size_t)(s * 32) * Ksz + k0, &As[s * 2048 + tid * 8]);
#pragma unroll
    for (int s = 0; s < 2; ++s)
      gl_lds16(Bg + (size_t)(s * 32) * Ksz + k0, &Bs[s * 2048 + tid * 8]);
    __syncthreads();
#pragma unroll
    for (int ks = 0; ks < 2; ++ks) {
      bf16x8 af[4], bfr[2];
#pragma unroll
      for (int i = 0; i < 4; ++i) {
        int ar = wm + i * 16 + lr;
        af[i] = *(const bf16x8*)&As[ar * 64 + (((ks * 4 + lg) ^ (ar & 7)) * 8)];
      }
#pragma unroll
      for (int i = 0; i < 2; ++i) {
        int br = wn + i * 16 + lr;
        bfr[i] = *(const bf16x8*)&Bs[br * 64 + (((ks * 4 + lg) ^ (br & 7)) * 8)];
      }
#pragma unroll
      for (int mi = 0; mi < 4; ++mi)
#pragma unroll
        for (int ni = 0; ni < 2; ++ni)
          acc[mi][ni] = __builtin_amdgcn_mfma_f32_16x16x32_bf16(af[mi], bfr[ni], acc[mi][ni], 0, 0, 0);
    }
    __syncthreads();
  }
#pragma unroll
  for (int mi = 0; mi < 4; ++mi)
#pragma unroll
    for (int ni = 0; ni < 2; ++ni)
#pragma unroll
      for (int r = 0; r < 4; ++r) {
        int row = m0 + wm + mi * 16 + lg * 4 + r;
        int col = n0 + wn + ni * 16 + lr;
        Cout[(size_t)row * Nsz + col] = acc[mi][ni][r];
      }
}

// ---- fused flash attention, swapped-QK^T (exp2 domain), 3-buffer counted-vmcnt
// pipeline (T4): prefetch depth 2, s_waitcnt vmcnt(4) + raw s_barrier per iter —
// never drains the VMEM queue in the main loop. Far-tile zero-C bias fold.
__global__ __launch_bounds__(256, 3) void k_attn(const unsigned short* __restrict__ Qb,
                                                 const unsigned short* __restrict__ Kb,
                                                 const unsigned short* __restrict__ Vt,
                                                 const float* __restrict__ bias_tab,
                                                 const float* __restrict__ maskadd,
                                                 const int* __restrict__ maskall,
                                                 unsigned short* __restrict__ Ob) {
  __shared__ unsigned short Ks[3][4096];   // [64 phys keys][64 dk], XOR-swizzled chunks
  __shared__ unsigned short Vs[3][4096];   // [64 dk][64 keys natural], XOR-swizzled
  __shared__ float biasw[384];             // near band: biasw[d+191]
  int qt = blockIdx.x, bh = blockIdx.y;
  int b = bh / NH, h = bh % NH;
  int tid = threadIdx.x, wave = tid >> 6, lane = tid & 63;
  int lr = lane & 15, lg = lane >> 4;
  int q0 = qt * 64;
  for (int i = tid; i < 383; i += 256) biasw[i] = bias_tab[h * 4095 + 1856 + i];
  float cFlo = bias_tab[h * 4095];          // d <= -91 saturated (bucket 15)
  float cFhi = bias_tab[h * 4095 + 4094];   // d >= +91 saturated (bucket 31)
  const unsigned short* Kbase = Kb + (size_t)(b * NL) * ND + h * NDK;
  const unsigned short* Vbase = Vt + (size_t)(b * NH + h) * NDK * NL;
  int srow = tid >> 3, spc = tid & 7;
  int sg = spc ^ (srow & 7);
  // key permutation: phys row srow stores logical key l0; +32 phys -> l0+4
  int l0 = (srow >> 4) * 32 + ((srow >> 2) & 3) * 8 + (srow & 3);
  const unsigned short* Kg0 = Kbase + (size_t)l0 * ND + sg * 8;
  const unsigned short* Kg1 = Kbase + (size_t)(l0 + 4) * ND + sg * 8;
  const unsigned short* Vg0 = Vbase + (size_t)srow * NL + sg * 8;
  const unsigned short* Vg1 = Vbase + (size_t)(32 + srow) * NL + sg * 8;
  bf16x8 aq[2];
  int qw = q0 + wave * 16;
#pragma unroll
  for (int ks = 0; ks < 2; ++ks)
    aq[ks] = *(const bf16x8*)&Qb[(size_t)(b * NL + qw + lr) * ND + h * NDK + ks * 32 + lg * 8];
  const float* cbase = maskadd + b * NL;
  int nomask = __builtin_amdgcn_readfirstlane(maskall[b]);
  f32x4 accO[4] = {};
  float mst = -1e30f, lst = 0.f;
  int bconst = lg * 8 - wave * 16 - lr + 191 - q0;   // near idx = kt*64 + subk + bconst
  int src0 = (lane & 48) | ((lane >> 2) & 12);
  // prologue: stage tiles 0 and 1 into bufs 0, 1 (8 loads in flight)
  gl_lds16(Kg0, &Ks[0][tid * 8]);
  gl_lds16(Kg1, &Ks[0][2048 + tid * 8]);
  gl_lds16(Vg0, &Vs[0][tid * 8]);
  gl_lds16(Vg1, &Vs[0][2048 + tid * 8]);
  {
    size_t kok = (size_t)64 * ND, kov = 64;
    gl_lds16(Kg0 + kok, &Ks[1][tid * 8]);
    gl_lds16(Kg1 + kok, &Ks[1][2048 + tid * 8]);
    gl_lds16(Vg0 + kov, &Vs[1][tid * 8]);
    gl_lds16(Vg1 + kov, &Vs[1][2048 + tid * 8]);
  }
  asm volatile("s_waitcnt vmcnt(4) lgkmcnt(0)" ::: "memory");  // tile0 + biasw ready
  __builtin_amdgcn_s_barrier();
  int cur = 0;
  const int NT = NL / 64;
  for (int kt = 0; kt < NT; ++kt) {
    float4 cv[2][2];
    if (!nomask) {
#pragma unroll
      for (int hf = 0; hf < 2; ++hf)
#pragma unroll
        for (int qd = 0; qd < 2; ++qd)
          cv[hf][qd] = *(const float4*)&cbase[kt * 64 + hf * 32 + lg * 8 + qd * 4];
    }
    bool pf = (kt + 2 < NT);
    if (pf) {
      int st = cur + 2; if (st >= 3) st -= 3;
      size_t kok = (size_t)(kt + 2) * 64 * ND;
      size_t kov = (size_t)(kt + 2) * 64;
      gl_lds16(Kg0 + kok, &Ks[st][tid * 8]);
      gl_lds16(Kg1 + kok, &Ks[st][2048 + tid * 8]);
      gl_lds16(Vg0 + kov, &Vs[st][tid * 8]);
      gl_lds16(Vg1 + kov, &Vs[st][2048 + tid * 8]);
    }
    int kt64 = kt * 64;
    bool farlo = (kt64 + 63 < q0 - 90), farhi = (kt64 > q0 + 153);
    float ctile = farlo ? cFlo : (farhi ? cFhi : 0.0f);
    f32x4 s[4];
    __builtin_amdgcn_s_setprio(1);
    if (nomask && (farlo || farhi)) {
      // far tile, no mask: MFMA from zero C; ctile folded into softmax scalars
      const f32x4 z = {0.f, 0.f, 0.f, 0.f};
#pragma unroll
      for (int ni = 0; ni < 4; ++ni) {
        int kr = ni * 16 + lr;
        bf16x8 bk0 = *(const bf16x8*)&Ks[cur][kr * 64 + ((lg ^ (lr & 7)) * 8)];
        bf16x8 bk1 = *(const bf16x8*)&Ks[cur][kr * 64 + (((4 + lg) ^ (lr & 7)) * 8)];
        s[ni] = __builtin_amdgcn_mfma_f32_16x16x32_bf16(bk0, aq[0], z, 0, 0, 0);
        s[ni] = __builtin_amdgcn_mfma_f32_16x16x32_bf16(bk1, aq[1], s[ni], 0, 0, 0);
      }
    } else {
      if (farlo || farhi) {
#pragma unroll
        for (int ni = 0; ni < 4; ++ni)
#pragma unroll
          for (int r = 0; r < 4; ++r) s[ni][r] = 0.f;   // ctile folded later
      } else {
#pragma unroll
        for (int ni = 0; ni < 4; ++ni)
#pragma unroll
          for (int r = 0; r < 4; ++r)
            s[ni][r] = biasw[kt64 + (ni & 1) * 32 + (ni >> 1) * 4 + r + bconst];
      }
      if (!nomask) {
#pragma unroll
        for (int ni = 0; ni < 4; ++ni)
#pragma unroll
          for (int r = 0; r < 4; ++r)
            s[ni][r] += ((const float*)&cv[ni & 1][ni >> 1])[r];
      }
#pragma unroll
      for (int ni = 0; ni < 4; ++ni) {
        int kr = ni * 16 + lr;
        bf16x8 bk0 = *(const bf16x8*)&Ks[cur][kr * 64 + ((lg ^ (lr & 7)) * 8)];
        bf16x8 bk1 = *(const bf16x8*)&Ks[cur][kr * 64 + (((4 + lg) ^ (lr & 7)) * 8)];
        s[ni] = __builtin_amdgcn_mfma_f32_16x16x32_bf16(bk0, aq[0], s[ni], 0, 0, 0);
        s[ni] = __builtin_amdgcn_mfma_f32_16x16x32_bf16(bk1, aq[1], s[ni], 0, 0, 0);
      }
    }
    __builtin_amdgcn_s_setprio(0);
    // row-max (lane owns 16 of 64 keys of q-row lr); true score = s + ctile
    f32x4 t0, t1;
#pragma unroll
    for (int r = 0; r < 4; ++r) t0[r] = fmaxf(s[0][r], s[1][r]);
#pragma unroll
    for (int r = 0; r < 4; ++r) t1[r] = fmaxf(s[2][r], s[3][r]);
#pragma unroll
    for (int r = 0; r < 4; ++r) t0[r] = fmaxf(t0[r], t1[r]);
    float pmax = fmaxf(fmaxf(t0[0], t0[1]), fmaxf(t0[2], t0[3]));
    pmax = fmaxf(pmax, __shfl_xor(pmax, 16));
    pmax = fmaxf(pmax, __shfl_xor(pmax, 32));
    float pm2 = pmax + ctile;
    if (!__all(pm2 - mst <= 8.0f)) {
      float mnew = fmaxf(mst, pm2);
      float sc = fexp2(mst - mnew);
      float scB[4];
#pragma unroll
      for (int r = 0; r < 4; ++r) scB[r] = __shfl(sc, src0 | r);
#pragma unroll
      for (int ni = 0; ni < 4; ++ni)
#pragma unroll
        for (int r = 0; r < 4; ++r) accO[ni][r] *= scB[r];
      lst *= sc;
      mst = mnew;
    }
    float msub = mst - ctile;
#pragma unroll
    for (int ni = 0; ni < 4; ++ni)
#pragma unroll
      for (int r = 0; r < 4; ++r) s[ni][r] = fexp2(s[ni][r] - msub);
    // tree-sum (depth 5)
    f32x4 ta = s[0] + s[1];
    f32x4 tb = s[2] + s[3];
    ta = ta + tb;
    float ps = (ta[0] + ta[1]) + (ta[2] + ta[3]);
    ps += __shfl_xor(ps, 16);
    ps += __shfl_xor(ps, 32);
    lst += ps;
    // pack P: lane's 16 values are exactly its PV A-fragments (key permutation)
    unsigned pw[8];
#pragma unroll
    for (int ni = 0; ni < 4; ++ni) {
      unsigned a, c;
      asm("v_cvt_pk_bf16_f32 %0, %1, %2" : "=v"(a) : "v"(s[ni][0]), "v"(s[ni][1]));
      asm("v_cvt_pk_bf16_f32 %0, %1, %2" : "=v"(c) : "v"(s[ni][2]), "v"(s[ni][3]));
      pw[ni * 2] = a; pw[ni * 2 + 1] = c;
    }
    u32x4 apw0 = {pw[0], pw[1], pw[4], pw[5]};
    u32x4 apw1 = {pw[2], pw[3], pw[6], pw[7]};
    bf16x8 ap0 = __builtin_bit_cast(bf16x8, apw0);
    bf16x8 ap1 = __builtin_bit_cast(bf16x8, apw1);
    // O += P @ V
    __builtin_amdgcn_s_setprio(1);
#pragma unroll
    for (int ni = 0; ni < 4; ++ni) {
      int vr = ni * 16 + lr;
      bf16x8 bv0 = *(const bf16x8*)&Vs[cur][vr * 64 + ((lg ^ (lr & 7)) * 8)];
      bf16x8 bv1 = *(const bf16x8*)&Vs[cur][vr * 64 + (((4 + lg) ^ (lr & 7)) * 8)];
      accO[ni] = __builtin_amdgcn_mfma_f32_16x16x32_bf16(ap0, bv0, accO[ni], 0, 0, 0);
      accO[ni] = __builtin_amdgcn_mfma_f32_16x16x32_bf16(ap1, bv1, accO[ni], 0, 0, 0);
    }
    __builtin_amdgcn_s_setprio(0);
    // counted wait: stage(t+1) complete, stage(t+2)'s 4 loads stay in flight
    if (pf) asm volatile("s_waitcnt vmcnt(4)" ::: "memory");
    else    asm volatile("s_waitcnt vmcnt(0)" ::: "memory");
    __builtin_amdgcn_s_barrier();
    cur = (cur == 2) ? 0 : cur + 1;
  }
  float linv = 1.0f / lst;
  float lB[4];
#pragma unroll
  for (int r = 0; r < 4; ++r) lB[r] = __shfl(linv, src0 | r);
#pragma unroll
  for (int ni = 0; ni < 4; ++ni)
#pragma unroll
    for (int r = 0; r < 4; ++r) {
      int qg = qw + lg * 4 + r;
      int col = h * NDK + ni * 16 + lr;
      Ob[(size_t)(b * NL + qg) * ND + col] = f2bf(accO[ni][r] * lB[r]);
    }
}

extern "C" void kernel_launch(void* const* d_in, const int* in_sizes, int n_in,
                              void* d_out, int out_size, void* d_ws, size_t ws_size,
                              hipStream_t stream) {
  const float* query  = (const float*)d_in[0];
  const float* keyval = (const float*)d_in[1];
  const int*   mask   = (const int*)d_in[2];
  const float* Wq     = (const float*)d_in[3];
  const float* Wk     = (const float*)d_in[4];
  const float* Wv     = (const float*)d_in[5];
  const float* Wo     = (const float*)d_in[6];
  const float* rel    = (const float*)d_in[7];

  char* ws = (char*)d_ws;
  unsigned short* q_bf  = (unsigned short*)(ws);              // 4096x768 bf16
  unsigned short* kv_bf = (unsigned short*)(ws + 6291456);
  unsigned short* Wq_t  = (unsigned short*)(ws + 12582912);   // [N][K] bf16 (x 0.125*log2e)
  unsigned short* Wk_t  = (unsigned short*)(ws + 13762560);
  unsigned short* Wv_t  = (unsigned short*)(ws + 14942208);
  unsigned short* Wo_t  = (unsigned short*)(ws + 16121856);
  unsigned short* Qb    = (unsigned short*)(ws + 17301504);   // [B,L,H,DK]
  unsigned short* Kb    = (unsigned short*)(ws + 23592960);
  unsigned short* Vt    = (unsigned short*)(ws + 29884416);   // [B,768,L]
  unsigned short* Ob    = (unsigned short*)(ws + 36175872);   // [B,L,H*DK]
  float* bias_tab       = (float*)(ws + 42467328);            // [H][4095], x log2e
  float* maskadd        = (float*)(ws + 42663936);            // [B][L]
  int*   maskall        = (int*)(ws + 42680320);              // [B]

  k_prep<<<dim3(8642), dim3(256), 0, stream>>>(query, keyval, Wq, Wk, Wv, Wo, rel, mask,
                                               q_bf, kv_bf, Wq_t, Wk_t, Wv_t, Wo_t,
                                               bias_tab, maskadd, maskall);
  k_gemm_qkv<<<dim3(32, 18), dim3(256), 0, stream>>>(q_bf, kv_bf, Wq_t, Qb, Kb, Vt);
  k_attn<<<dim3(32, 24), dim3(256), 0, stream>>>(Qb, Kb, Vt, bias_tab, maskadd, maskall, Ob);
  k_gemm<<<dim3(32, 12), dim3(256), 0, stream>>>(Ob, Wo_t, (float*)d_out, NM, ND, ND);
}

// Round 10
// 113.277 us; speedup vs baseline: 2.3376x; 1.0409x over previous
//
#include <hip/hip_runtime.h>
#include <stdint.h>

typedef __attribute__((ext_vector_type(8))) short bf16x8;
typedef __attribute__((ext_vector_type(4))) float f32x4;
typedef __attribute__((ext_vector_type(4))) unsigned int u32x4;

#define NB 2
#define NL 2048
#define ND 768
#define NH 12
#define NDK 64
#define NM 4096   // NB*NL
#define LOG2E 1.4426950408889634f

__device__ __forceinline__ unsigned short f2bf(float f) {
  unsigned u = __builtin_bit_cast(unsigned, f);
  u += 0x7FFFu + ((u >> 16) & 1u);          // RNE
  return (unsigned short)(u >> 16);
}

__device__ __forceinline__ float fexp2(float x) {
  float r;
  asm("v_exp_f32 %0, %1" : "=v"(r) : "v"(x));
  return r;
}

// cross-lane xor-32 combines. NOTE: the permlane32_swap asm version was broken —
// "+v"(a),"+v"(b) with a==b lets regalloc coalesce both into ONE vgpr, making the
// swap self-referential (lane loses its own value). Off the hot path -> shfl is fine.
__device__ __forceinline__ float xmax32(float x) { return fmaxf(x, __shfl_xor(x, 32)); }
__device__ __forceinline__ float xsum32(float x) { return x + __shfl_xor(x, 32); }

__device__ __forceinline__ void gl_lds16(const unsigned short* g, unsigned short* l) {
  __builtin_amdgcn_global_load_lds((const __attribute__((address_space(1))) void*)g,
                                   (__attribute__((address_space(3))) void*)l, 16, 0, 0);
}

// ---- merged prep: conv (0..6143) | wt (6144..8447) | bias (8448..8639) | maskadd (8640..8641)
__global__ __launch_bounds__(256) void k_prep(const float* __restrict__ query,
                                              const float* __restrict__ keyval,
                                              const float* __restrict__ Wq,
                                              const float* __restrict__ Wk,
                                              const float* __restrict__ Wv,
                                              const float* __restrict__ Wo,
                                              const float* __restrict__ rel_emb,
                                              const int* __restrict__ mask,
                                              unsigned short* __restrict__ q_bf,
                                              unsigned short* __restrict__ kv_bf,
                                              unsigned short* __restrict__ Wq_t,
                                              unsigned short* __restrict__ Wk_t,
                                              unsigned short* __restrict__ Wv_t,
                                              unsigned short* __restrict__ Wo_t,
                                              float* __restrict__ bias_tab,
                                              float* __restrict__ maskadd,
                                              int* __restrict__ maskall) {
  __shared__ float shbuf[32 * 33];
  int blk = blockIdx.x, tid = threadIdx.x;
  if (blk < 6144) {
    int y = blk / 3072;
    int i = (blk - y * 3072) * 256 + tid;
    const float* src = y ? keyval : query;
    unsigned short* dst = y ? kv_bf : q_bf;
    float4 v = ((const float4*)src)[i];
    ushort4 o;
    o.x = f2bf(v.x); o.y = f2bf(v.y); o.z = f2bf(v.z); o.w = f2bf(v.w);
    ((ushort4*)dst)[i] = o;
  } else if (blk < 8448) {
    int rel = blk - 6144;
    int z = rel / 576, r2 = rel - z * 576;
    int bx = (r2 % 24) * 32, by = (r2 / 24) * 32;
    const float* w = (z == 0) ? Wq : (z == 1) ? Wk : (z == 2) ? Wv : Wo;
    unsigned short* o = (z == 0) ? Wq_t : (z == 1) ? Wk_t : (z == 2) ? Wv_t : Wo_t;
    float scale = (z == 0) ? 0.125f * LOG2E : 1.0f;
    int tx = tid & 31, ty = tid >> 5;
    float (*t)[33] = (float(*)[33])shbuf;
    for (int r = 0; r < 32; r += 8)
      t[ty + r][tx] = w[(by + ty + r) * ND + bx + tx];
    __syncthreads();
    for (int r = 0; r < 32; r += 8)
      o[(bx + ty + r) * ND + by + tx] = f2bf(t[tx][ty + r] * scale);
  } else if (blk < 8640) {
    int idx = (blk - 8448) * 256 + tid;
    if (idx >= 4095 * NH) return;
    int h = idx % NH;
    int di = idx / NH;
    int rel = di - 2047;          // rel = k - q
    int n = -rel;
    int ret = 0;
    if (n < 0) { ret = 16; n = -n; }
    int b;
    if (n < 8) {
      b = ret + n;
    } else {
      int v = (n >= 91) ? 7 : (n >= 64) ? 6 : (n >= 46) ? 5 : (n >= 32) ? 4
            : (n >= 23) ? 3 : (n >= 16) ? 2 : (n >= 12) ? 1 : 0;
      b = ret + 8 + v;
    }
    bias_tab[h * 4095 + di] = rel_emb[b * NH + h] * LOG2E;
  } else {
    int b = blk - 8640;
    int* red = (int*)shbuf;
    int acc = 1;
    for (int i = tid; i < NL; i += 256) {
      int m = mask[b * NL + i];
      maskadd[b * NL + i] = m ? 0.0f : -1e30f;
      acc &= (m != 0) ? 1 : 0;
    }
    red[tid] = acc;
    __syncthreads();
    for (int s2 = 128; s2 > 0; s2 >>= 1) {
      if (tid < s2) red[tid] &= red[tid + s2];
      __syncthreads();
    }
    if (tid == 0) maskall[b] = red[0];
  }
}

// ---- fused QKV GEMM, 128x128 tile: grid (32, 18); y/6 = {Q,K,V}. BK=64, gl_lds w16.
__global__ __launch_bounds__(256) void k_gemm_qkv(const unsigned short* __restrict__ q_bf,
                                                  const unsigned short* __restrict__ kv_bf,
                                                  const unsigned short* __restrict__ Wt,
                                                  unsigned short* __restrict__ Qb,
                                                  unsigned short* __restrict__ Kb,
                                                  unsigned short* __restrict__ Vt) {
  __shared__ unsigned short As[8192];   // [128 rows][64 k], 16 KB
  __shared__ unsigned short Bs[8192];
  int tid = threadIdx.x;
  int wave = tid >> 6, lane = tid & 63;
  int lr = lane & 15, lg = lane >> 4;
  int m0 = blockIdx.x * 128;
  int z = blockIdx.y / 6;                  // 0=Q, 1=K, 2=V
  int nc0 = (blockIdx.y % 6) * 128;
  const unsigned short* A  = (z == 0) ? q_bf : kv_bf;
  const unsigned short* Bt = Wt + (size_t)blockIdx.y * 128 * ND;
  int wm = (wave >> 1) * 64, wn = (wave & 1) * 64;
  int srow = tid >> 3, spc = tid & 7;
  int sg = spc ^ (srow & 7);
  const unsigned short* Ag = A  + (size_t)(m0 + srow) * ND + sg * 8;
  const unsigned short* Bg = Bt + (size_t)srow * ND + sg * 8;
  f32x4 acc[4][4] = {};
  for (int t = 0; t < ND / 64; ++t) {
    int k0 = t * 64;
#pragma unroll
    for (int s = 0; s < 4; ++s) {
      gl_lds16(Ag + (size_t)(s * 32) * ND + k0, &As[s * 2048 + tid * 8]);
      gl_lds16(Bg + (size_t)(s * 32) * ND + k0, &Bs[s * 2048 + tid * 8]);
    }
    __syncthreads();
#pragma unroll
    for (int ks = 0; ks < 2; ++ks) {
      bf16x8 af[4], bfr[4];
#pragma unroll
      for (int i = 0; i < 4; ++i) {
        int ar = wm + i * 16 + lr;
        af[i] = *(const bf16x8*)&As[ar * 64 + (((ks * 4 + lg) ^ (ar & 7)) * 8)];
        int br = wn + i * 16 + lr;
        bfr[i] = *(const bf16x8*)&Bs[br * 64 + (((ks * 4 + lg) ^ (br & 7)) * 8)];
      }
#pragma unroll
      for (int mi = 0; mi < 4; ++mi)
#pragma unroll
        for (int ni = 0; ni < 4; ++ni)
          acc[mi][ni] = __builtin_amdgcn_mfma_f32_16x16x32_bf16(af[mi], bfr[ni], acc[mi][ni], 0, 0, 0);
    }
    __syncthreads();
  }
#pragma unroll
  for (int mi = 0; mi < 4; ++mi)
#pragma unroll
    for (int ni = 0; ni < 4; ++ni)
#pragma unroll
      for (int r = 0; r < 4; ++r) {
        int row = m0 + wm + mi * 16 + lg * 4 + r;
        int col = nc0 + wn + ni * 16 + lr;
        unsigned short v = f2bf(acc[mi][ni][r]);
        if (z == 0) {
          Qb[(size_t)row * ND + col] = v;
        } else if (z == 1) {
          Kb[(size_t)row * ND + col] = v;
        } else {
          int bb = row >> 11, l = row & 2047;
          Vt[(((size_t)bb * ND + col) << 11) + l] = v;
        }
      }
}

// ---- out-proj GEMM: C[M,N] fp32 = A[M,K] bf16 * Bt[N,K]^T. 128x64 tile, BK=64.
__global__ __launch_bounds__(256) void k_gemm(const unsigned short* __restrict__ A,
                                              const unsigned short* __restrict__ Bt,
                                              float* __restrict__ Cout,
                                              int Msz, int Nsz, int Ksz) {
  __shared__ unsigned short As[8192];
  __shared__ unsigned short Bs[4096];
  int tid = threadIdx.x;
  int wave = tid >> 6, lane = tid & 63;
  int lr = lane & 15, lg = lane >> 4;
  int m0 = blockIdx.x * 128, n0 = blockIdx.y * 64;
  int wm = (wave >> 1) * 64, wn = (wave & 1) * 32;
  int srow = tid >> 3, spc = tid & 7;
  int sg = spc ^ (srow & 7);
  const unsigned short* Ag = A  + (size_t)(m0 + srow) * Ksz + sg * 8;
  const unsigned short* Bg = Bt + (size_t)(n0 + srow) * Ksz + sg * 8;
  f32x4 acc[4][2] = {};
  for (int t = 0; t < Ksz / 64; ++t) {
    int k0 = t * 64;
#pragma unroll
    for (int s = 0; s < 4; ++s)
      gl_lds16(Ag + (size_t)(s * 32) * Ksz + k0, &As[s * 2048 + tid * 8]);
#pragma unroll
    for (int s = 0; s < 2; ++s)
      gl_lds16(Bg + (size_t)(s * 32) * Ksz + k0, &Bs[s * 2048 + tid * 8]);
    __syncthreads();
#pragma unroll
    for (int ks = 0; ks < 2; ++ks) {
      bf16x8 af[4], bfr[2];
#pragma unroll
      for (int i = 0; i < 4; ++i) {
        int ar = wm + i * 16 + lr;
        af[i] = *(const bf16x8*)&As[ar * 64 + (((ks * 4 + lg) ^ (ar & 7)) * 8)];
      }
#pragma unroll
      for (int i = 0; i < 2; ++i) {
        int br = wn + i * 16 + lr;
        bfr[i] = *(const bf16x8*)&Bs[br * 64 + (((ks * 4 + lg) ^ (br & 7)) * 8)];
      }
#pragma unroll
      for (int mi = 0; mi < 4; ++mi)
#pragma unroll
        for (int ni = 0; ni < 2; ++ni)
          acc[mi][ni] = __builtin_amdgcn_mfma_f32_16x16x32_bf16(af[mi], bfr[ni], acc[mi][ni], 0, 0, 0);
    }
    __syncthreads();
  }
#pragma unroll
  for (int mi = 0; mi < 4; ++mi)
#pragma unroll
    for (int ni = 0; ni < 2; ++ni)
#pragma unroll
      for (int r = 0; r < 4; ++r) {
        int row = m0 + wm + mi * 16 + lg * 4 + r;
        int col = n0 + wn + ni * 16 + lr;
        Cout[(size_t)row * Nsz + col] = acc[mi][ni][r];
      }
}

// ---- fused flash attention: swapped-QK^T (exp2), 3-buffer counted-vmcnt pipeline,
// far-tile zero-C bias fold, and a FULLY LANE-LOCAL softmax common path:
// defer-check via per-lane local max (+ wave vote), per-lane partial row-sum,
// cross-lane reduces only in the rare rescale branch and the epilogue.
__global__ __launch_bounds__(256, 3) void k_attn(const unsigned short* __restrict__ Qb,
                                                 const unsigned short* __restrict__ Kb,
                                                 const unsigned short* __restrict__ Vt,
                                                 const float* __restrict__ bias_tab,
                                                 const float* __restrict__ maskadd,
                                                 const int* __restrict__ maskall,
                                                 unsigned short* __restrict__ Ob) {
  __shared__ unsigned short Ks[3][4096];   // [64 phys keys][64 dk], XOR-swizzled chunks
  __shared__ unsigned short Vs[3][4096];   // [64 dk][64 keys natural], XOR-swizzled
  __shared__ float biasw[384];             // near band: biasw[d+191]
  int qt = blockIdx.x, bh = blockIdx.y;
  int b = bh / NH, h = bh % NH;
  int tid = threadIdx.x, wave = tid >> 6, lane = tid & 63;
  int lr = lane & 15, lg = lane >> 4;
  int q0 = qt * 64;
  for (int i = tid; i < 383; i += 256) biasw[i] = bias_tab[h * 4095 + 1856 + i];
  float cFlo = bias_tab[h * 4095];          // d <= -91 saturated (bucket 15)
  float cFhi = bias_tab[h * 4095 + 4094];   // d >= +91 saturated (bucket 31)
  const unsigned short* Kbase = Kb + (size_t)(b * NL) * ND + h * NDK;
  const unsigned short* Vbase = Vt + (size_t)(b * NH + h) * NDK * NL;
  int srow = tid >> 3, spc = tid & 7;
  int sg = spc ^ (srow & 7);
  // key permutation: phys row srow stores logical key l0; +32 phys -> l0+4
  int l0 = (srow >> 4) * 32 + ((srow >> 2) & 3) * 8 + (srow & 3);
  const unsigned short* Kg0 = Kbase + (size_t)l0 * ND + sg * 8;
  const unsigned short* Kg1 = Kbase + (size_t)(l0 + 4) * ND + sg * 8;
  const unsigned short* Vg0 = Vbase + (size_t)srow * NL + sg * 8;
  const unsigned short* Vg1 = Vbase + (size_t)(32 + srow) * NL + sg * 8;
  bf16x8 aq[2];
  int qw = q0 + wave * 16;
#pragma unroll
  for (int ks = 0; ks < 2; ++ks)
    aq[ks] = *(const bf16x8*)&Qb[(size_t)(b * NL + qw + lr) * ND + h * NDK + ks * 32 + lg * 8];
  const float* cbase = maskadd + b * NL;
  int nomask = __builtin_amdgcn_readfirstlane(maskall[b]);
  f32x4 accO[4] = {};
  float mst = -1e30f, lstl = 0.f;          // per-lane partial row-sum (16 keys/lane)
  int bconst = lg * 8 - wave * 16 - lr + 191 - q0;   // near idx = kt*64 + subk + bconst
  int src0 = (lane & 48) | ((lane >> 2) & 12);
  // prologue: stage tiles 0 and 1 into bufs 0, 1 (8 loads in flight)
  gl_lds16(Kg0, &Ks[0][tid * 8]);
  gl_lds16(Kg1, &Ks[0][2048 + tid * 8]);
  gl_lds16(Vg0, &Vs[0][tid * 8]);
  gl_lds16(Vg1, &Vs[0][2048 + tid * 8]);
  {
    size_t kok = (size_t)64 * ND, kov = 64;
    gl_lds16(Kg0 + kok, &Ks[1][tid * 8]);
    gl_lds16(Kg1 + kok, &Ks[1][2048 + tid * 8]);
    gl_lds16(Vg0 + kov, &Vs[1][tid * 8]);
    gl_lds16(Vg1 + kov, &Vs[1][2048 + tid * 8]);
  }
  asm volatile("s_waitcnt vmcnt(4) lgkmcnt(0)" ::: "memory");  // tile0 + biasw ready
  __builtin_amdgcn_s_barrier();
  int cur = 0;
  const int NT = NL / 64;
  for (int kt = 0; kt < NT; ++kt) {
    float4 cv[2][2];
    if (!nomask) {
#pragma unroll
      for (int hf = 0; hf < 2; ++hf)
#pragma unroll
        for (int qd = 0; qd < 2; ++qd)
          cv[hf][qd] = *(const float4*)&cbase[kt * 64 + hf * 32 + lg * 8 + qd * 4];
    }
    bool pf = (kt + 2 < NT);
    if (pf) {
      int st = cur + 2; if (st >= 3) st -= 3;
      size_t kok = (size_t)(kt + 2) * 64 * ND;
      size_t kov = (size_t)(kt + 2) * 64;
      gl_lds16(Kg0 + kok, &Ks[st][tid * 8]);
      gl_lds16(Kg1 + kok, &Ks[st][2048 + tid * 8]);
      gl_lds16(Vg0 + kov, &Vs[st][tid * 8]);
      gl_lds16(Vg1 + kov, &Vs[st][2048 + tid * 8]);
    }
    int kt64 = kt * 64;
    bool farlo = (kt64 + 63 < q0 - 90), farhi = (kt64 > q0 + 153);
    float ctile = farlo ? cFlo : (farhi ? cFhi : 0.0f);
    f32x4 s[4];
    __builtin_amdgcn_s_setprio(1);
    if (nomask && (farlo || farhi)) {
      // far tile, no mask: MFMA from zero C; ctile folded into softmax scalars
      const f32x4 z = {0.f, 0.f, 0.f, 0.f};
#pragma unroll
      for (int ni = 0; ni < 4; ++ni) {
        int kr = ni * 16 + lr;
        bf16x8 bk0 = *(const bf16x8*)&Ks[cur][kr * 64 + ((lg ^ (lr & 7)) * 8)];
        bf16x8 bk1 = *(const bf16x8*)&Ks[cur][kr * 64 + (((4 + lg) ^ (lr & 7)) * 8)];
        s[ni] = __builtin_amdgcn_mfma_f32_16x16x32_bf16(bk0, aq[0], z, 0, 0, 0);
        s[ni] = __builtin_amdgcn_mfma_f32_16x16x32_bf16(bk1, aq[1], s[ni], 0, 0, 0);
      }
    } else {
      if (farlo || farhi) {
#pragma unroll
        for (int ni = 0; ni < 4; ++ni)
#pragma unroll
          for (int r = 0; r < 4; ++r) s[ni][r] = 0.f;   // ctile folded later
      } else {
#pragma unroll
        for (int ni = 0; ni < 4; ++ni)
#pragma unroll
          for (int r = 0; r < 4; ++r)
            s[ni][r] = biasw[kt64 + (ni & 1) * 32 + (ni >> 1) * 4 + r + bconst];
      }
      if (!nomask) {
#pragma unroll
        for (int ni = 0; ni < 4; ++ni)
#pragma unroll
          for (int r = 0; r < 4; ++r)
            s[ni][r] += ((const float*)&cv[ni & 1][ni >> 1])[r];
      }
#pragma unroll
      for (int ni = 0; ni < 4; ++ni) {
        int kr = ni * 16 + lr;
        bf16x8 bk0 = *(const bf16x8*)&Ks[cur][kr * 64 + ((lg ^ (lr & 7)) * 8)];
        bf16x8 bk1 = *(const bf16x8*)&Ks[cur][kr * 64 + (((4 + lg) ^ (lr & 7)) * 8)];
        s[ni] = __builtin_amdgcn_mfma_f32_16x16x32_bf16(bk0, aq[0], s[ni], 0, 0, 0);
        s[ni] = __builtin_amdgcn_mfma_f32_16x16x32_bf16(bk1, aq[1], s[ni], 0, 0, 0);
      }
    }
    __builtin_amdgcn_s_setprio(0);
    // lane-local max over this lane's 16 keys (NO cross-lane on common path)
    f32x4 t0, t1;
#pragma unroll
    for (int r = 0; r < 4; ++r) t0[r] = fmaxf(s[0][r], s[1][r]);
#pragma unroll
    for (int r = 0; r < 4; ++r) t1[r] = fmaxf(s[2][r], s[3][r]);
#pragma unroll
    for (int r = 0; r < 4; ++r) t0[r] = fmaxf(t0[r], t1[r]);
    float lm = fmaxf(fmaxf(t0[0], t0[1]), fmaxf(t0[2], t0[3]));
    // defer-check: __all over lanes covers every row's max — equivalent condition
    if (!__all(lm + ctile - mst <= 8.0f)) {
      float pmax = fmaxf(lm, __shfl_xor(lm, 16));
      pmax = xmax32(pmax);
      float pm2 = pmax + ctile;
      float mnew = fmaxf(mst, pm2);
      float sc = fexp2(mst - mnew);
      float scB[4];
#pragma unroll
      for (int r = 0; r < 4; ++r) scB[r] = __shfl(sc, src0 | r);
#pragma unroll
      for (int ni = 0; ni < 4; ++ni)
#pragma unroll
        for (int r = 0; r < 4; ++r) accO[ni][r] *= scB[r];
      lstl *= sc;            // per-lane partial scales by its row's (uniform) sc
      mst = mnew;
    }
    float msub = mst - ctile;
#pragma unroll
    for (int ni = 0; ni < 4; ++ni)
#pragma unroll
      for (int r = 0; r < 4; ++r) s[ni][r] = fexp2(s[ni][r] - msub);
    // lane-local partial sum (cross-lane reduce deferred to epilogue)
    {
      f32x4 ta = s[0] + s[1];
      f32x4 tb = s[2] + s[3];
      ta = ta + tb;
      lstl += (ta[0] + ta[1]) + (ta[2] + ta[3]);
    }
    // pack P: lane's 16 values are exactly its PV A-fragments (key permutation)
    unsigned pw[8];
#pragma unroll
    for (int ni = 0; ni < 4; ++ni) {
      unsigned a, c;
      asm("v_cvt_pk_bf16_f32 %0, %1, %2" : "=v"(a) : "v"(s[ni][0]), "v"(s[ni][1]));
      asm("v_cvt_pk_bf16_f32 %0, %1, %2" : "=v"(c) : "v"(s[ni][2]), "v"(s[ni][3]));
      pw[ni * 2] = a; pw[ni * 2 + 1] = c;
    }
    u32x4 apw0 = {pw[0], pw[1], pw[4], pw[5]};
    u32x4 apw1 = {pw[2], pw[3], pw[6], pw[7]};
    bf16x8 ap0 = __builtin_bit_cast(bf16x8, apw0);
    bf16x8 ap1 = __builtin_bit_cast(bf16x8, apw1);
    // O += P @ V
    __builtin_amdgcn_s_setprio(1);
#pragma unroll
    for (int ni = 0; ni < 4; ++ni) {
      int vr = ni * 16 + lr;
      bf16x8 bv0 = *(const bf16x8*)&Vs[cur][vr * 64 + ((lg ^ (lr & 7)) * 8)];
      bf16x8 bv1 = *(const bf16x8*)&Vs[cur][vr * 64 + (((4 + lg) ^ (lr & 7)) * 8)];
      accO[ni] = __builtin_amdgcn_mfma_f32_16x16x32_bf16(ap0, bv0, accO[ni], 0, 0, 0);
      accO[ni] = __builtin_amdgcn_mfma_f32_16x16x32_bf16(ap1, bv1, accO[ni], 0, 0, 0);
    }
    __builtin_amdgcn_s_setprio(0);
    // counted wait: stage(t+1) complete, stage(t+2)'s 4 loads stay in flight
    if (pf) asm volatile("s_waitcnt vmcnt(4)" ::: "memory");
    else    asm volatile("s_waitcnt vmcnt(0)" ::: "memory");
    __builtin_amdgcn_s_barrier();
    cur = (cur == 2) ? 0 : cur + 1;
  }
  // epilogue: one cross-lane row-sum, then broadcast 1/l to accO's row layout
  float lst = lstl + __shfl_xor(lstl, 16);
  lst = xsum32(lst);
  float linv = 1.0f / lst;
  float lB[4];
#pragma unroll
  for (int r = 0; r < 4; ++r) lB[r] = __shfl(linv, src0 | r);
#pragma unroll
  for (int ni = 0; ni < 4; ++ni)
#pragma unroll
    for (int r = 0; r < 4; ++r) {
      int qg = qw + lg * 4 + r;
      int col = h * NDK + ni * 16 + lr;
      Ob[(size_t)(b * NL + qg) * ND + col] = f2bf(accO[ni][r] * lB[r]);
    }
}

extern "C" void kernel_launch(void* const* d_in, const int* in_sizes, int n_in,
                              void* d_out, int out_size, void* d_ws, size_t ws_size,
                              hipStream_t stream) {
  const float* query  = (const float*)d_in[0];
  const float* keyval = (const float*)d_in[1];
  const int*   mask   = (const int*)d_in[2];
  const float* Wq     = (const float*)d_in[3];
  const float* Wk     = (const float*)d_in[4];
  const float* Wv     = (const float*)d_in[5];
  const float* Wo     = (const float*)d_in[6];
  const float* rel    = (const float*)d_in[7];

  char* ws = (char*)d_ws;
  unsigned short* q_bf  = (unsigned short*)(ws);              // 4096x768 bf16
  unsigned short* kv_bf = (unsigned short*)(ws + 6291456);
  unsigned short* Wq_t  = (unsigned short*)(ws + 12582912);   // [N][K] bf16 (x 0.125*log2e)
  unsigned short* Wk_t  = (unsigned short*)(ws + 13762560);
  unsigned short* Wv_t  = (unsigned short*)(ws + 14942208);
  unsigned short* Wo_t  = (unsigned short*)(ws + 16121856);
  unsigned short* Qb    = (unsigned short*)(ws + 17301504);   // [B,L,H,DK]
  unsigned short* Kb    = (unsigned short*)(ws + 23592960);
  unsigned short* Vt    = (unsigned short*)(ws + 29884416);   // [B,768,L]
  unsigned short* Ob    = (unsigned short*)(ws + 36175872);   // [B,L,H*DK]
  float* bias_tab       = (float*)(ws + 42467328);            // [H][4095], x log2e
  float* maskadd        = (float*)(ws + 42663936);            // [B][L]
  int*   maskall        = (int*)(ws + 42680320);              // [B]

  k_prep<<<dim3(8642), dim3(256), 0, stream>>>(query, keyval, Wq, Wk, Wv, Wo, rel, mask,
                                               q_bf, kv_bf, Wq_t, Wk_t, Wv_t, Wo_t,
                                               bias_tab, maskadd, maskall);
  k_gemm_qkv<<<dim3(32, 18), dim3(256), 0, stream>>>(q_bf, kv_bf, Wq_t, Qb, Kb, Vt);
  k_attn<<<dim3(32, 24), dim3(256), 0, stream>>>(Qb, Kb, Vt, bias_tab, maskadd, maskall, Ob);
  k_gemm<<<dim3(32, 12), dim3(256), 0, stream>>>(Ob, Wo_t, (float*)d_out, NM, ND, ND);
}